// Round 1
// baseline (2022.430 us; speedup 1.0000x reference)
//
#include <hip/hip_runtime.h>
#include <hip/hip_bf16.h>
#include <math.h>

#define D_MODEL 1024
#define D_STATE 16
#define D_CONV 4
#define D_INNER 2048
#define DT_RANK 64
#define L_SEQ 2048
#define N_BATCH 2
#define M_ROWS (N_BATCH * L_SEQ)   // 4096

// ---------------------------------------------------------------------------
// Generic fp32 GEMM: C[M,N] = A[M,K] * B[N,K]^T  (both row-major, K-contig)
// MODE 0: plain    MODE 1: softplus(acc + bias[col])
// 64x64 tile, 256 threads, 4x4 microtile, BK=16.
// Requires: M % 64 == 0, K % 16 == 0. N guarded.
// ---------------------------------------------------------------------------
#define BM 64
#define BN 64
#define BK 16
#define LDS_PITCH 68   // 68 floats: 16B-aligned rows (68*4=272=17*16), breaks pow2 banks

template <int MODE>
__global__ __launch_bounds__(256) void gemm_bt(
    const float* __restrict__ A, const float* __restrict__ B,
    float* __restrict__ C, const float* __restrict__ bias,
    int M, int N, int K, int lda, int ldb, int ldc)
{
    __shared__ float As[BK][LDS_PITCH];
    __shared__ float Bs[BK][LDS_PITCH];
    const int tid  = threadIdx.x;
    const int row0 = blockIdx.y * BM;
    const int col0 = blockIdx.x * BN;
    const int ar = tid >> 2;          // 0..63 : tile row for loads
    const int ak = (tid & 3) * 4;     // 0,4,8,12 : k offset (float4)
    const int ty = tid >> 4;          // 0..15
    const int tx = tid & 15;          // 0..15

    float acc[4][4];
    #pragma unroll
    for (int i = 0; i < 4; ++i)
        #pragma unroll
        for (int j = 0; j < 4; ++j) acc[i][j] = 0.f;

    for (int k0 = 0; k0 < K; k0 += BK) {
        float4 av = *(const float4*)(A + (size_t)(row0 + ar) * lda + k0 + ak);
        float4 bv;
        const int gcol = col0 + ar;
        if (gcol < N) bv = *(const float4*)(B + (size_t)gcol * ldb + k0 + ak);
        else          bv = make_float4(0.f, 0.f, 0.f, 0.f);

        __syncthreads();   // protect previous iteration's reads
        As[ak + 0][ar] = av.x; As[ak + 1][ar] = av.y;
        As[ak + 2][ar] = av.z; As[ak + 3][ar] = av.w;
        Bs[ak + 0][ar] = bv.x; Bs[ak + 1][ar] = bv.y;
        Bs[ak + 2][ar] = bv.z; Bs[ak + 3][ar] = bv.w;
        __syncthreads();

        #pragma unroll
        for (int kk = 0; kk < BK; ++kk) {
            const float4 a4 = *(const float4*)&As[kk][ty * 4];
            const float4 b4 = *(const float4*)&Bs[kk][tx * 4];
            const float a[4] = {a4.x, a4.y, a4.z, a4.w};
            const float b[4] = {b4.x, b4.y, b4.z, b4.w};
            #pragma unroll
            for (int i = 0; i < 4; ++i)
                #pragma unroll
                for (int j = 0; j < 4; ++j)
                    acc[i][j] = fmaf(a[i], b[j], acc[i][j]);
        }
    }

    #pragma unroll
    for (int i = 0; i < 4; ++i) {
        const int r = row0 + ty * 4 + i;
        #pragma unroll
        for (int j = 0; j < 4; ++j) {
            const int c = col0 + tx * 4 + j;
            if (c < N) {
                float v = acc[i][j];
                if (MODE == 1) {
                    v += bias[c];
                    v = (v > 20.f) ? v : log1pf(__expf(v));   // softplus
                }
                C[(size_t)r * ldc + c] = v;
            }
        }
    }
}

// ---------------------------------------------------------------------------
// Depthwise causal conv (width 4) + bias + SiLU.  Reads x = xz[:, :, 0:2048].
// One thread per (b,l,c), coalesced in c.
// ---------------------------------------------------------------------------
__global__ __launch_bounds__(256) void conv_silu_kernel(
    const float* __restrict__ xz, const float* __restrict__ conv_w,
    const float* __restrict__ conv_b, float* __restrict__ u)
{
    const int idx = blockIdx.x * 256 + threadIdx.x;   // B*L*D_INNER
    const int c  = idx & (D_INNER - 1);
    const int ml = idx >> 11;                         // b*L + l
    const int l  = ml & (L_SEQ - 1);
    float acc = conv_b[c];
    const float* w = conv_w + c * D_CONV;
    #pragma unroll
    for (int j = 0; j < D_CONV; ++j) {
        const int ll = l - (D_CONV - 1) + j;
        if (ll >= 0)
            acc = fmaf(xz[(size_t)(ml - (D_CONV - 1) + j) * (2 * D_INNER) + c], w[j], acc);
    }
    u[(size_t)ml * D_INNER + c] = acc / (1.f + __expf(-acc));   // silu
}

// ---------------------------------------------------------------------------
// Selective scan.  16 lanes per (b,d): lane n holds state h[n].
// Block = 256 threads = 16 d-channels of one batch.  Grid = B * (D_INNER/16).
// Timesteps staged through LDS in chunks of 128 (vectorized cooperative load).
// Epilogue fuses  y = (scan + u*D) * silu(z)  on lane n==0 of each group.
// ---------------------------------------------------------------------------
#define CHUNK 128

__global__ __launch_bounds__(256) void scan_kernel(
    const float* __restrict__ delta, const float* __restrict__ u,
    const float* __restrict__ xdbl,  const float* __restrict__ xz,
    const float* __restrict__ A_log, const float* __restrict__ Dp,
    float* __restrict__ y)
{
    __shared__ float ds_[CHUNK][16];
    __shared__ float us_[CHUNK][16];
    __shared__ float bs_[CHUNK][16];
    __shared__ float cs_[CHUNK][16];

    const int tid   = threadIdx.x;
    const int bid   = blockIdx.x;          // 0..255
    const int b     = bid >> 7;            // / (D_INNER/16)
    const int dbase = (bid & 127) << 4;
    const int n  = tid & 15;               // state index within group
    const int dl = (tid >> 4) & 15;        // local d-channel
    const int d  = dbase + dl;

    const float Acoef = -__expf(A_log[d * D_STATE + n]);  // A_log stores ln(), A=-exp
    const float Dd    = Dp[d];
    float h = 0.f;

    for (int c0 = 0; c0 < L_SEQ; c0 += CHUNK) {
        __syncthreads();
        // cooperative vectorized load of the chunk: 512 float4 per array
        #pragma unroll
        for (int q = 0; q < 2; ++q) {
            const int f  = tid + q * 256;      // 0..511
            const int t  = f >> 2;             // 0..127
            const int dq = (f & 3) * 4;        // 0,4,8,12
            const size_t m = (size_t)(b * L_SEQ + c0 + t);
            const float4 dv = *(const float4*)(delta + m * D_INNER + dbase + dq);
            const float4 uv = *(const float4*)(u     + m * D_INNER + dbase + dq);
            const float4 bv = *(const float4*)(xdbl + m * 96 + DT_RANK + dq);
            const float4 cv = *(const float4*)(xdbl + m * 96 + DT_RANK + D_STATE + dq);
            *(float4*)&ds_[t][dq] = dv;
            *(float4*)&us_[t][dq] = uv;
            *(float4*)&bs_[t][dq] = bv;
            *(float4*)&cs_[t][dq] = cv;
        }
        __syncthreads();

        #pragma unroll 4
        for (int t = 0; t < CHUNK; ++t) {
            const float dt_v = ds_[t][dl];
            const float u_v  = us_[t][dl];
            const float Bn   = bs_[t][n];
            const float Cn   = cs_[t][n];
            const float dA = __expf(dt_v * Acoef);
            h = fmaf(dA, h, dt_v * u_v * Bn);
            float v = h * Cn;
            v += __shfl_xor(v, 1);
            v += __shfl_xor(v, 2);
            v += __shfl_xor(v, 4);
            v += __shfl_xor(v, 8);
            if (n == 0) {
                const size_t m = (size_t)(b * L_SEQ + c0 + t);
                const float z   = xz[m * (2 * D_INNER) + D_INNER + d];
                const float sig = 1.f / (1.f + __expf(-z));
                y[m * D_INNER + d] = (v + u_v * Dd) * (z * sig);
            }
        }
    }
}

// ---------------------------------------------------------------------------
// Launch
// ---------------------------------------------------------------------------
extern "C" void kernel_launch(void* const* d_in, const int* in_sizes, int n_in,
                              void* d_out, int out_size, void* d_ws, size_t ws_size,
                              hipStream_t stream)
{
    const float* hs        = (const float*)d_in[0];  // (2,2048,1024)
    const float* in_proj_w = (const float*)d_in[1];  // (4096,1024)
    const float* conv_w    = (const float*)d_in[2];  // (2048,1,4)
    const float* conv_b    = (const float*)d_in[3];  // (2048,)
    const float* x_proj_w  = (const float*)d_in[4];  // (96,2048)
    const float* dt_proj_w = (const float*)d_in[5];  // (2048,64)
    const float* dt_proj_b = (const float*)d_in[6];  // (2048,)
    const float* A_log     = (const float*)d_in[7];  // (2048,16)
    const float* D_param   = (const float*)d_in[8];  // (2048,)
    const float* out_proj_w= (const float*)d_in[9];  // (1024,2048)
    float* out = (float*)d_out;                      // (2,2048,1024)

    // workspace layout (floats)
    float* xz    = (float*)d_ws;                          // 4096*4096
    float* u     = xz    + (size_t)M_ROWS * (2 * D_INNER);// 4096*2048
    float* xdbl  = u     + (size_t)M_ROWS * D_INNER;      // 4096*96
    float* delta = xdbl  + (size_t)M_ROWS * 96;           // 4096*2048
    float* y     = delta + (size_t)M_ROWS * D_INNER;      // 4096*2048

    const dim3 blk(256);

    // 1) xz = hs @ in_proj_w^T   (4096 x 4096, K=1024)
    gemm_bt<0><<<dim3(64, 64), blk, 0, stream>>>(
        hs, in_proj_w, xz, nullptr, M_ROWS, 2 * D_INNER, D_MODEL,
        D_MODEL, D_MODEL, 2 * D_INNER);

    // 2) u = silu(causal_conv(x) + conv_b)
    conv_silu_kernel<<<(M_ROWS * D_INNER) / 256, blk, 0, stream>>>(
        xz, conv_w, conv_b, u);

    // 3) x_dbl = u @ x_proj_w^T   (4096 x 96, K=2048)
    gemm_bt<0><<<dim3(2, 64), blk, 0, stream>>>(
        u, x_proj_w, xdbl, nullptr, M_ROWS, 96, D_INNER,
        D_INNER, D_INNER, 96);

    // 4) delta = softplus(dt @ dt_proj_w^T + dt_proj_b)  (4096 x 2048, K=64)
    gemm_bt<1><<<dim3(32, 64), blk, 0, stream>>>(
        xdbl, dt_proj_w, delta, dt_proj_b, M_ROWS, D_INNER, DT_RANK,
        96, DT_RANK, D_INNER);

    // 5) selective scan + gating -> y
    scan_kernel<<<N_BATCH * (D_INNER / 16), blk, 0, stream>>>(
        delta, u, xdbl, xz, A_log, D_param, y);

    // 6) out = y @ out_proj_w^T   (4096 x 1024, K=2048)
    gemm_bt<0><<<dim3(16, 64), blk, 0, stream>>>(
        y, out_proj_w, out, nullptr, M_ROWS, D_MODEL, D_INNER,
        D_INNER, D_INNER, D_MODEL);
}

// Round 2
// 1182.232 us; speedup vs baseline: 1.7107x; 1.7107x over previous
//
#include <hip/hip_runtime.h>
#include <hip/hip_bf16.h>
#include <math.h>

#define D_MODEL 1024
#define D_STATE 16
#define D_CONV 4
#define D_INNER 2048
#define DT_RANK 64
#define L_SEQ 2048
#define N_BATCH 2
#define M_ROWS (N_BATCH * L_SEQ)   // 4096

#define N_CHUNK 32                 // chunks over L
#define CLEN (L_SEQ / N_CHUNK)     // 64 timesteps per chunk

// ---------------------------------------------------------------------------
// Generic fp32 GEMM: C[M,N] = A[M,K] * B[N,K]^T  (both row-major, K-contig)
// MODE 0: plain    MODE 1: softplus(acc + bias[col])
// 64x64 tile, 256 threads, 4x4 microtile, BK=16.
// ---------------------------------------------------------------------------
#define BM 64
#define BN 64
#define BK 16
#define LDS_PITCH 68

template <int MODE>
__global__ __launch_bounds__(256) void gemm_bt(
    const float* __restrict__ A, const float* __restrict__ B,
    float* __restrict__ C, const float* __restrict__ bias,
    int M, int N, int K, int lda, int ldb, int ldc)
{
    __shared__ float As[BK][LDS_PITCH];
    __shared__ float Bs[BK][LDS_PITCH];
    const int tid  = threadIdx.x;
    const int row0 = blockIdx.y * BM;
    const int col0 = blockIdx.x * BN;
    const int ar = tid >> 2;
    const int ak = (tid & 3) * 4;
    const int ty = tid >> 4;
    const int tx = tid & 15;

    float acc[4][4];
    #pragma unroll
    for (int i = 0; i < 4; ++i)
        #pragma unroll
        for (int j = 0; j < 4; ++j) acc[i][j] = 0.f;

    for (int k0 = 0; k0 < K; k0 += BK) {
        float4 av = *(const float4*)(A + (size_t)(row0 + ar) * lda + k0 + ak);
        float4 bv;
        const int gcol = col0 + ar;
        if (gcol < N) bv = *(const float4*)(B + (size_t)gcol * ldb + k0 + ak);
        else          bv = make_float4(0.f, 0.f, 0.f, 0.f);

        __syncthreads();
        As[ak + 0][ar] = av.x; As[ak + 1][ar] = av.y;
        As[ak + 2][ar] = av.z; As[ak + 3][ar] = av.w;
        Bs[ak + 0][ar] = bv.x; Bs[ak + 1][ar] = bv.y;
        Bs[ak + 2][ar] = bv.z; Bs[ak + 3][ar] = bv.w;
        __syncthreads();

        #pragma unroll
        for (int kk = 0; kk < BK; ++kk) {
            const float4 a4 = *(const float4*)&As[kk][ty * 4];
            const float4 b4 = *(const float4*)&Bs[kk][tx * 4];
            const float a[4] = {a4.x, a4.y, a4.z, a4.w};
            const float b[4] = {b4.x, b4.y, b4.z, b4.w};
            #pragma unroll
            for (int i = 0; i < 4; ++i)
                #pragma unroll
                for (int j = 0; j < 4; ++j)
                    acc[i][j] = fmaf(a[i], b[j], acc[i][j]);
        }
    }

    #pragma unroll
    for (int i = 0; i < 4; ++i) {
        const int r = row0 + ty * 4 + i;
        #pragma unroll
        for (int j = 0; j < 4; ++j) {
            const int c = col0 + tx * 4 + j;
            if (c < N) {
                float v = acc[i][j];
                if (MODE == 1) {
                    v += bias[c];
                    v = (v > 20.f) ? v : log1pf(__expf(v));
                }
                C[(size_t)r * ldc + c] = v;
            }
        }
    }
}

// ---------------------------------------------------------------------------
// Depthwise causal conv (width 4) + bias + SiLU.
// ---------------------------------------------------------------------------
__global__ __launch_bounds__(256) void conv_silu_kernel(
    const float* __restrict__ xz, const float* __restrict__ conv_w,
    const float* __restrict__ conv_b, float* __restrict__ u)
{
    const int idx = blockIdx.x * 256 + threadIdx.x;
    const int c  = idx & (D_INNER - 1);
    const int ml = idx >> 11;
    const int l  = ml & (L_SEQ - 1);
    float acc = conv_b[c];
    const float* w = conv_w + c * D_CONV;
    #pragma unroll
    for (int j = 0; j < D_CONV; ++j) {
        const int ll = l - (D_CONV - 1) + j;
        if (ll >= 0)
            acc = fmaf(xz[(size_t)(ml - (D_CONV - 1) + j) * (2 * D_INNER) + c], w[j], acc);
    }
    u[(size_t)ml * D_INNER + c] = acc / (1.f + __expf(-acc));
}

// ---------------------------------------------------------------------------
// Chunked selective scan.
// Block = 256 threads = 16 d-channels x 16 states; one block per (b, d-group,
// chunk).  PHASE 0: compute per-chunk (P = prod dA, Q = local scan from 0).
// PHASE 1: re-run local scan from Hin, emit gated y.
// Dynamic LDS: 3 (phase0) or 4 (phase1) arrays of CLEN*16 floats.
// ---------------------------------------------------------------------------
template <int PHASE>
__global__ __launch_bounds__(256) void scan_chunk_kernel(
    const float* __restrict__ delta, const float* __restrict__ u,
    const float* __restrict__ xdbl,  const float* __restrict__ xz,
    const float* __restrict__ A_log, const float* __restrict__ Dp,
    float* __restrict__ P, float* __restrict__ Q,
    const float* __restrict__ Hin, float* __restrict__ y)
{
    extern __shared__ float smem[];
    float* ds_ = smem;                    // [CLEN][16] per-d delta
    float* us_ = smem + CLEN * 16;        // [CLEN][16] per-d u
    float* bs_ = smem + 2 * CLEN * 16;    // [CLEN][16] B_t[n]
    float* cs_ = smem + 3 * CLEN * 16;    // [CLEN][16] C_t[n] (phase 1 only)

    const int tid   = threadIdx.x;
    const int bid   = blockIdx.x;              // B * 128 * N_CHUNK
    const int c     = bid & (N_CHUNK - 1);
    const int rest  = bid >> 5;                // log2(N_CHUNK)=5
    const int b     = rest >> 7;
    const int dbase = (rest & 127) << 4;
    const int n  = tid & 15;
    const int dl = tid >> 4;                   // 0..15 local d-channel
    const int d  = dbase + dl;
    const int t0 = c * CLEN;

    const float Acoef = -__expf(A_log[d * D_STATE + n]);
    const size_t sidx = (((size_t)(b * N_CHUNK + c) * D_INNER + dbase) << 4) + tid;

    // cooperative vectorized load of the chunk: CLEN*16 = 1024 floats = 256 f4
    {
        const int t  = tid >> 2;
        const int dq = (tid & 3) * 4;
        const size_t m = (size_t)(b * L_SEQ + t0 + t);
        *(float4*)&ds_[t * 16 + dq] = *(const float4*)(delta + m * D_INNER + dbase + dq);
        *(float4*)&us_[t * 16 + dq] = *(const float4*)(u     + m * D_INNER + dbase + dq);
        *(float4*)&bs_[t * 16 + dq] = *(const float4*)(xdbl + m * 96 + DT_RANK + dq);
        if (PHASE == 1)
            *(float4*)&cs_[t * 16 + dq] = *(const float4*)(xdbl + m * 96 + DT_RANK + D_STATE + dq);
    }
    __syncthreads();

    if (PHASE == 0) {
        float h = 0.f, Pacc = 1.f;
        #pragma unroll 4
        for (int t = 0; t < CLEN; ++t) {
            const float dt_v = ds_[t * 16 + dl];
            const float u_v  = us_[t * 16 + dl];
            const float Bn   = bs_[t * 16 + n];
            const float dA = __expf(dt_v * Acoef);
            Pacc *= dA;
            h = fmaf(dA, h, dt_v * u_v * Bn);
        }
        P[sidx] = Pacc;
        Q[sidx] = h;
    } else {
        const float Dd = Dp[d];
        float h = Hin[sidx];
        #pragma unroll 4
        for (int t = 0; t < CLEN; ++t) {
            const float dt_v = ds_[t * 16 + dl];
            const float u_v  = us_[t * 16 + dl];
            const float Bn   = bs_[t * 16 + n];
            const float Cn   = cs_[t * 16 + n];
            const float dA = __expf(dt_v * Acoef);
            h = fmaf(dA, h, dt_v * u_v * Bn);
            float v = h * Cn;
            v += __shfl_xor(v, 1);
            v += __shfl_xor(v, 2);
            v += __shfl_xor(v, 4);
            v += __shfl_xor(v, 8);
            if (n == 0) {
                const size_t m = (size_t)(b * L_SEQ + t0 + t);
                const float z   = xz[m * (2 * D_INNER) + D_INNER + d];
                const float sig = 1.f / (1.f + __expf(-z));
                y[m * D_INNER + d] = (v + u_v * Dd) * (z * sig);
            }
        }
    }
}

// ---------------------------------------------------------------------------
// Sequential chunk composition: h_in[c] for each (b,d,n).
// ---------------------------------------------------------------------------
__global__ __launch_bounds__(256) void scan_combine_kernel(
    const float* __restrict__ P, const float* __restrict__ Q,
    float* __restrict__ Hin)
{
    const int idx = blockIdx.x * 256 + threadIdx.x;  // (b*2048 + d)*16 + n
    const int b   = idx >> 15;
    const int dn  = idx & 32767;
    float h = 0.f;
    #pragma unroll
    for (int c = 0; c < N_CHUNK; ++c) {
        const size_t o = ((size_t)(b * N_CHUNK + c) << 15) + dn;
        Hin[o] = h;
        h = fmaf(P[o], h, Q[o]);
    }
}

// ---------------------------------------------------------------------------
// Launch
// ---------------------------------------------------------------------------
extern "C" void kernel_launch(void* const* d_in, const int* in_sizes, int n_in,
                              void* d_out, int out_size, void* d_ws, size_t ws_size,
                              hipStream_t stream)
{
    const float* hs        = (const float*)d_in[0];
    const float* in_proj_w = (const float*)d_in[1];
    const float* conv_w    = (const float*)d_in[2];
    const float* conv_b    = (const float*)d_in[3];
    const float* x_proj_w  = (const float*)d_in[4];
    const float* dt_proj_w = (const float*)d_in[5];
    const float* dt_proj_b = (const float*)d_in[6];
    const float* A_log     = (const float*)d_in[7];
    const float* D_param   = (const float*)d_in[8];
    const float* out_proj_w= (const float*)d_in[9];
    float* out = (float*)d_out;

    // workspace layout (floats)
    float* xz    = (float*)d_ws;                          // 4096*4096
    float* u     = xz    + (size_t)M_ROWS * (2 * D_INNER);
    float* xdbl  = u     + (size_t)M_ROWS * D_INNER;      // 4096*96
    float* delta = xdbl  + (size_t)M_ROWS * 96;
    float* y     = delta + (size_t)M_ROWS * D_INNER;
    float* Pws   = y     + (size_t)M_ROWS * D_INNER;      // B*NC*D_INNER*16
    float* Qws   = Pws   + (size_t)N_BATCH * N_CHUNK * D_INNER * 16;
    float* Hin   = Qws   + (size_t)N_BATCH * N_CHUNK * D_INNER * 16;

    const dim3 blk(256);

    // 1) xz = hs @ in_proj_w^T
    gemm_bt<0><<<dim3(64, 64), blk, 0, stream>>>(
        hs, in_proj_w, xz, nullptr, M_ROWS, 2 * D_INNER, D_MODEL,
        D_MODEL, D_MODEL, 2 * D_INNER);

    // 2) u = silu(causal_conv(x) + conv_b)
    conv_silu_kernel<<<(M_ROWS * D_INNER) / 256, blk, 0, stream>>>(
        xz, conv_w, conv_b, u);

    // 3) x_dbl = u @ x_proj_w^T
    gemm_bt<0><<<dim3(2, 64), blk, 0, stream>>>(
        u, x_proj_w, xdbl, nullptr, M_ROWS, 96, D_INNER,
        D_INNER, D_INNER, 96);

    // 4) delta = softplus(dt @ dt_proj_w^T + dt_proj_b)
    gemm_bt<1><<<dim3(32, 64), blk, 0, stream>>>(
        xdbl, dt_proj_w, delta, dt_proj_b, M_ROWS, D_INNER, DT_RANK,
        96, DT_RANK, D_INNER);

    // 5) chunked selective scan
    const int scan_blocks = N_BATCH * (D_INNER / 16) * N_CHUNK;  // 8192
    scan_chunk_kernel<0><<<scan_blocks, blk, 3 * CLEN * 16 * 4, stream>>>(
        delta, u, xdbl, xz, A_log, D_param, Pws, Qws, nullptr, nullptr);
    scan_combine_kernel<<<(N_BATCH * D_INNER * 16) / 256, blk, 0, stream>>>(
        Pws, Qws, Hin);
    scan_chunk_kernel<1><<<scan_blocks, blk, 4 * CLEN * 16 * 4, stream>>>(
        delta, u, xdbl, xz, A_log, D_param, nullptr, nullptr, Hin, y);

    // 6) out = y @ out_proj_w^T
    gemm_bt<0><<<dim3(16, 64), blk, 0, stream>>>(
        y, out_proj_w, out, nullptr, M_ROWS, D_MODEL, D_INNER,
        D_INNER, D_INNER, D_MODEL);
}

// Round 3
// 597.424 us; speedup vs baseline: 3.3853x; 1.9789x over previous
//
#include <hip/hip_runtime.h>
#include <hip/hip_bf16.h>
#include <math.h>

#define D_MODEL 1024
#define D_STATE 16
#define D_CONV 4
#define D_INNER 2048
#define DT_RANK 64
#define L_SEQ 2048
#define N_BATCH 2
#define M_ROWS (N_BATCH * L_SEQ)   // 4096

#define N_CHUNK 32                 // chunks over L
#define CLEN (L_SEQ / N_CHUNK)     // 64 timesteps per chunk

typedef __attribute__((ext_vector_type(8))) __bf16 bf16x8;
typedef __attribute__((ext_vector_type(4))) float f32x4;

__device__ __forceinline__ unsigned short f2b(float f) {
    unsigned int u = __float_as_uint(f);
    unsigned int r = (u + 0x7fffu + ((u >> 16) & 1u)) >> 16;   // RNE
    return (unsigned short)r;
}

// addrspace casts for global_load_lds (generic->as1 / as3 via integer, CK-style)
#define AS1G(p) ((const __attribute__((address_space(1))) void*)(uintptr_t)(p))
#define AS3L(p) ((__attribute__((address_space(3))) void*)(unsigned int)(uintptr_t)(p))

// ---------------------------------------------------------------------------
// fp32 -> bf16 cast, float4 granularity
// ---------------------------------------------------------------------------
__global__ __launch_bounds__(256) void cvt_bf16_kernel(
    const float* __restrict__ src, unsigned short* __restrict__ dst, int n4)
{
    const int i = blockIdx.x * 256 + threadIdx.x;
    if (i < n4) {
        const float4 f = ((const float4*)src)[i];
        ushort4 o;
        o.x = f2b(f.x); o.y = f2b(f.y); o.z = f2b(f.z); o.w = f2b(f.w);
        ((ushort4*)dst)[i] = o;
    }
}

// ---------------------------------------------------------------------------
// bf16 MFMA GEMM (m97 structure): C[M,N] = A[M,K] * B[N,K]^T, fp32 out.
// 128x128 tile, BK=32, 256 threads = 4 waves, each wave 64x64 via 4x4 MFMAs.
// Staging: global_load_lds width=16, unpadded row-major [128][32] bf16 tiles.
// Requires M%128==0, N%128==0, K%32==0.
// ---------------------------------------------------------------------------
__global__ __launch_bounds__(256) void gemm_mfma_bt(
    const unsigned short* __restrict__ A, const unsigned short* __restrict__ B,
    float* __restrict__ C, int M, int N, int K)
{
    __shared__ unsigned short As[128 * 32];
    __shared__ unsigned short Bs[128 * 32];

    const int tid  = threadIdx.x;
    const int wave = tid >> 6;
    const int lane = tid & 63;
    const int row0 = blockIdx.y * 128;
    const int col0 = blockIdx.x * 128;
    const int wr = (wave >> 1) * 64;       // wave quadrant origin
    const int wc = (wave & 1) * 64;
    const int lm = lane & 15;              // fragment row/col
    const int kg = (lane >> 4) * 8;        // fragment k-offset

    f32x4 acc[4][4];
    #pragma unroll
    for (int i = 0; i < 4; ++i)
        #pragma unroll
        for (int j = 0; j < 4; ++j)
            acc[i][j] = (f32x4){0.f, 0.f, 0.f, 0.f};

    // staging chunk ids: chunk c (16B = 8 bf16) -> row c>>2, k-offset (c&3)*8
    const int c0 = tid;            // round 0
    const int c1 = tid + 256;      // round 1
    const int r0_ = c0 >> 2, kq0 = (c0 & 3) * 8;
    const int r1_ = c1 >> 2, kq1 = (c1 & 3) * 8;
    // wave-uniform LDS bases (elements): round r -> r*2048 + wave*512
    unsigned short* lA0 = As + wave * 512;
    unsigned short* lA1 = As + 2048 + wave * 512;
    unsigned short* lB0 = Bs + wave * 512;
    unsigned short* lB1 = Bs + 2048 + wave * 512;

    for (int k0 = 0; k0 < K; k0 += 32) {
        __syncthreads();   // previous iteration's LDS reads done
        __builtin_amdgcn_global_load_lds(AS1G(A + (size_t)(row0 + r0_) * K + k0 + kq0), AS3L(lA0), 16, 0, 0);
        __builtin_amdgcn_global_load_lds(AS1G(A + (size_t)(row0 + r1_) * K + k0 + kq1), AS3L(lA1), 16, 0, 0);
        __builtin_amdgcn_global_load_lds(AS1G(B + (size_t)(col0 + r0_) * K + k0 + kq0), AS3L(lB0), 16, 0, 0);
        __builtin_amdgcn_global_load_lds(AS1G(B + (size_t)(col0 + r1_) * K + k0 + kq1), AS3L(lB1), 16, 0, 0);
        __syncthreads();   // drains vmcnt before barrier

        bf16x8 af[4], bf[4];
        #pragma unroll
        for (int i = 0; i < 4; ++i) {
            af[i] = *(const bf16x8*)&As[(wr + i * 16 + lm) * 32 + kg];
            bf[i] = *(const bf16x8*)&Bs[(wc + i * 16 + lm) * 32 + kg];
        }
        #pragma unroll
        for (int i = 0; i < 4; ++i)
            #pragma unroll
            for (int j = 0; j < 4; ++j)
                acc[i][j] = __builtin_amdgcn_mfma_f32_16x16x32_bf16(af[i], bf[j], acc[i][j], 0, 0, 0);
    }

    // C/D mapping: col = lane&15, row = (lane>>4)*4 + reg
    #pragma unroll
    for (int i = 0; i < 4; ++i) {
        const int r = row0 + wr + i * 16 + (lane >> 4) * 4;
        #pragma unroll
        for (int j = 0; j < 4; ++j) {
            const int cc = col0 + wc + j * 16 + lm;
            #pragma unroll
            for (int v = 0; v < 4; ++v)
                C[(size_t)(r + v) * N + cc] = acc[i][j][v];
        }
    }
}

// ---------------------------------------------------------------------------
// fp32 fallback GEMM (x_proj, dt_proj): C[M,N] = A[M,K]*B[N,K]^T
// MODE 0: plain    MODE 1: softplus(acc + bias[col])
// ---------------------------------------------------------------------------
#define BK 16
#define LDS_PITCH 68

template <int MODE>
__global__ __launch_bounds__(256) void gemm_bt(
    const float* __restrict__ A, const float* __restrict__ B,
    float* __restrict__ C, const float* __restrict__ bias,
    int M, int N, int K, int lda, int ldb, int ldc)
{
    __shared__ float As[BK][LDS_PITCH];
    __shared__ float Bs[BK][LDS_PITCH];
    const int tid  = threadIdx.x;
    const int row0 = blockIdx.y * 64;
    const int col0 = blockIdx.x * 64;
    const int ar = tid >> 2;
    const int ak = (tid & 3) * 4;
    const int ty = tid >> 4;
    const int tx = tid & 15;

    float acc[4][4];
    #pragma unroll
    for (int i = 0; i < 4; ++i)
        #pragma unroll
        for (int j = 0; j < 4; ++j) acc[i][j] = 0.f;

    for (int k0 = 0; k0 < K; k0 += BK) {
        float4 av = *(const float4*)(A + (size_t)(row0 + ar) * lda + k0 + ak);
        float4 bv;
        const int gcol = col0 + ar;
        if (gcol < N) bv = *(const float4*)(B + (size_t)gcol * ldb + k0 + ak);
        else          bv = make_float4(0.f, 0.f, 0.f, 0.f);

        __syncthreads();
        As[ak + 0][ar] = av.x; As[ak + 1][ar] = av.y;
        As[ak + 2][ar] = av.z; As[ak + 3][ar] = av.w;
        Bs[ak + 0][ar] = bv.x; Bs[ak + 1][ar] = bv.y;
        Bs[ak + 2][ar] = bv.z; Bs[ak + 3][ar] = bv.w;
        __syncthreads();

        #pragma unroll
        for (int kk = 0; kk < BK; ++kk) {
            const float4 a4 = *(const float4*)&As[kk][ty * 4];
            const float4 b4 = *(const float4*)&Bs[kk][tx * 4];
            const float a[4] = {a4.x, a4.y, a4.z, a4.w};
            const float b[4] = {b4.x, b4.y, b4.z, b4.w};
            #pragma unroll
            for (int i = 0; i < 4; ++i)
                #pragma unroll
                for (int j = 0; j < 4; ++j)
                    acc[i][j] = fmaf(a[i], b[j], acc[i][j]);
        }
    }

    #pragma unroll
    for (int i = 0; i < 4; ++i) {
        const int r = row0 + ty * 4 + i;
        #pragma unroll
        for (int j = 0; j < 4; ++j) {
            const int c = col0 + tx * 4 + j;
            if (c < N) {
                float v = acc[i][j];
                if (MODE == 1) {
                    v += bias[c];
                    v = (v > 20.f) ? v : log1pf(__expf(v));
                }
                C[(size_t)r * ldc + c] = v;
            }
        }
    }
}

// ---------------------------------------------------------------------------
// Depthwise causal conv (width 4) + bias + SiLU.
// ---------------------------------------------------------------------------
__global__ __launch_bounds__(256) void conv_silu_kernel(
    const float* __restrict__ xz, const float* __restrict__ conv_w,
    const float* __restrict__ conv_b, float* __restrict__ u)
{
    const int idx = blockIdx.x * 256 + threadIdx.x;
    const int c  = idx & (D_INNER - 1);
    const int ml = idx >> 11;
    const int l  = ml & (L_SEQ - 1);
    float acc = conv_b[c];
    const float* w = conv_w + c * D_CONV;
    #pragma unroll
    for (int j = 0; j < D_CONV; ++j) {
        const int ll = l - (D_CONV - 1) + j;
        if (ll >= 0)
            acc = fmaf(xz[(size_t)(ml - (D_CONV - 1) + j) * (2 * D_INNER) + c], w[j], acc);
    }
    u[(size_t)ml * D_INNER + c] = acc / (1.f + __expf(-acc));
}

// ---------------------------------------------------------------------------
// Chunked selective scan (see round 1).  PHASE 1 now emits y in bf16.
// ---------------------------------------------------------------------------
template <int PHASE>
__global__ __launch_bounds__(256) void scan_chunk_kernel(
    const float* __restrict__ delta, const float* __restrict__ u,
    const float* __restrict__ xdbl,  const float* __restrict__ xz,
    const float* __restrict__ A_log, const float* __restrict__ Dp,
    float* __restrict__ P, float* __restrict__ Q,
    const float* __restrict__ Hin, unsigned short* __restrict__ y)
{
    extern __shared__ float smem[];
    float* ds_ = smem;
    float* us_ = smem + CLEN * 16;
    float* bs_ = smem + 2 * CLEN * 16;
    float* cs_ = smem + 3 * CLEN * 16;

    const int tid   = threadIdx.x;
    const int bid   = blockIdx.x;
    const int c     = bid & (N_CHUNK - 1);
    const int rest  = bid >> 5;
    const int b     = rest >> 7;
    const int dbase = (rest & 127) << 4;
    const int n  = tid & 15;
    const int dl = tid >> 4;
    const int d  = dbase + dl;
    const int t0 = c * CLEN;

    const float Acoef = -__expf(A_log[d * D_STATE + n]);
    const size_t sidx = (((size_t)(b * N_CHUNK + c) * D_INNER + dbase) << 4) + tid;

    {
        const int t  = tid >> 2;
        const int dq = (tid & 3) * 4;
        const size_t m = (size_t)(b * L_SEQ + t0 + t);
        *(float4*)&ds_[t * 16 + dq] = *(const float4*)(delta + m * D_INNER + dbase + dq);
        *(float4*)&us_[t * 16 + dq] = *(const float4*)(u     + m * D_INNER + dbase + dq);
        *(float4*)&bs_[t * 16 + dq] = *(const float4*)(xdbl + m * 96 + DT_RANK + dq);
        if (PHASE == 1)
            *(float4*)&cs_[t * 16 + dq] = *(const float4*)(xdbl + m * 96 + DT_RANK + D_STATE + dq);
    }
    __syncthreads();

    if (PHASE == 0) {
        float h = 0.f, Pacc = 1.f;
        #pragma unroll 4
        for (int t = 0; t < CLEN; ++t) {
            const float dt_v = ds_[t * 16 + dl];
            const float u_v  = us_[t * 16 + dl];
            const float Bn   = bs_[t * 16 + n];
            const float dA = __expf(dt_v * Acoef);
            Pacc *= dA;
            h = fmaf(dA, h, dt_v * u_v * Bn);
        }
        P[sidx] = Pacc;
        Q[sidx] = h;
    } else {
        const float Dd = Dp[d];
        float h = Hin[sidx];
        #pragma unroll 4
        for (int t = 0; t < CLEN; ++t) {
            const float dt_v = ds_[t * 16 + dl];
            const float u_v  = us_[t * 16 + dl];
            const float Bn   = bs_[t * 16 + n];
            const float Cn   = cs_[t * 16 + n];
            const float dA = __expf(dt_v * Acoef);
            h = fmaf(dA, h, dt_v * u_v * Bn);
            float v = h * Cn;
            v += __shfl_xor(v, 1);
            v += __shfl_xor(v, 2);
            v += __shfl_xor(v, 4);
            v += __shfl_xor(v, 8);
            if (n == 0) {
                const size_t m = (size_t)(b * L_SEQ + t0 + t);
                const float z   = xz[m * (2 * D_INNER) + D_INNER + d];
                const float sig = 1.f / (1.f + __expf(-z));
                y[m * D_INNER + d] = f2b((v + u_v * Dd) * (z * sig));
            }
        }
    }
}

__global__ __launch_bounds__(256) void scan_combine_kernel(
    const float* __restrict__ P, const float* __restrict__ Q,
    float* __restrict__ Hin)
{
    const int idx = blockIdx.x * 256 + threadIdx.x;
    const int b   = idx >> 15;
    const int dn  = idx & 32767;
    float h = 0.f;
    #pragma unroll
    for (int c = 0; c < N_CHUNK; ++c) {
        const size_t o = ((size_t)(b * N_CHUNK + c) << 15) + dn;
        Hin[o] = h;
        h = fmaf(P[o], h, Q[o]);
    }
}

// ---------------------------------------------------------------------------
// Launch
// ---------------------------------------------------------------------------
extern "C" void kernel_launch(void* const* d_in, const int* in_sizes, int n_in,
                              void* d_out, int out_size, void* d_ws, size_t ws_size,
                              hipStream_t stream)
{
    const float* hs        = (const float*)d_in[0];
    const float* in_proj_w = (const float*)d_in[1];
    const float* conv_w    = (const float*)d_in[2];
    const float* conv_b    = (const float*)d_in[3];
    const float* x_proj_w  = (const float*)d_in[4];
    const float* dt_proj_w = (const float*)d_in[5];
    const float* dt_proj_b = (const float*)d_in[6];
    const float* A_log     = (const float*)d_in[7];
    const float* D_param   = (const float*)d_in[8];
    const float* out_proj_w= (const float*)d_in[9];
    float* out = (float*)d_out;

    // workspace layout (fp32 part)
    float* xz    = (float*)d_ws;                            // 16.8M f
    float* u     = xz    + (size_t)M_ROWS * (2 * D_INNER);  // 8.4M f
    float* xdbl  = u     + (size_t)M_ROWS * D_INNER;        // 393216 f
    float* delta = xdbl  + (size_t)M_ROWS * 96;             // 8.4M f
    float* Pws   = delta + (size_t)M_ROWS * D_INNER;        // 2.1M f
    float* Qws   = Pws   + (size_t)N_BATCH * N_CHUNK * D_INNER * 16;
    float* Hin   = Qws   + (size_t)N_BATCH * N_CHUNK * D_INNER * 16;
    // bf16 part
    unsigned short* opw_bf = (unsigned short*)(Hin + (size_t)N_BATCH * N_CHUNK * D_INNER * 16);
    unsigned short* y_bf   = opw_bf + (size_t)D_MODEL * D_INNER;
    // hs_bf/ipw_bf alias the delta region: consumed (in_proj) before delta is
    // written (dt_proj) — stream-ordered, safe.
    unsigned short* hs_bf  = (unsigned short*)delta;
    unsigned short* ipw_bf = hs_bf + (size_t)M_ROWS * D_MODEL;

    const dim3 blk(256);

    // 0) fp32 -> bf16 casts
    cvt_bf16_kernel<<<(M_ROWS * D_MODEL / 4 + 255) / 256, blk, 0, stream>>>(
        hs, hs_bf, M_ROWS * D_MODEL / 4);
    cvt_bf16_kernel<<<(2 * D_INNER * D_MODEL / 4 + 255) / 256, blk, 0, stream>>>(
        in_proj_w, ipw_bf, 2 * D_INNER * D_MODEL / 4);
    cvt_bf16_kernel<<<(D_MODEL * D_INNER / 4 + 255) / 256, blk, 0, stream>>>(
        out_proj_w, opw_bf, D_MODEL * D_INNER / 4);

    // 1) xz = hs @ in_proj_w^T   (bf16 MFMA)
    gemm_mfma_bt<<<dim3((2 * D_INNER) / 128, M_ROWS / 128), blk, 0, stream>>>(
        hs_bf, ipw_bf, xz, M_ROWS, 2 * D_INNER, D_MODEL);

    // 2) u = silu(causal_conv(x) + conv_b)
    conv_silu_kernel<<<(M_ROWS * D_INNER) / 256, blk, 0, stream>>>(
        xz, conv_w, conv_b, u);

    // 3) x_dbl = u @ x_proj_w^T   (fp32)
    gemm_bt<0><<<dim3(2, 64), blk, 0, stream>>>(
        u, x_proj_w, xdbl, nullptr, M_ROWS, 96, D_INNER,
        D_INNER, D_INNER, 96);

    // 4) delta = softplus(dt @ dt_proj_w^T + dt_proj_b)   (fp32)
    gemm_bt<1><<<dim3(32, 64), blk, 0, stream>>>(
        xdbl, dt_proj_w, delta, dt_proj_b, M_ROWS, D_INNER, DT_RANK,
        96, DT_RANK, D_INNER);

    // 5) chunked selective scan (phase1 writes bf16 y)
    const int scan_blocks = N_BATCH * (D_INNER / 16) * N_CHUNK;
    scan_chunk_kernel<0><<<scan_blocks, blk, 3 * CLEN * 16 * 4, stream>>>(
        delta, u, xdbl, xz, A_log, D_param, Pws, Qws, nullptr, nullptr);
    scan_combine_kernel<<<(N_BATCH * D_INNER * 16) / 256, blk, 0, stream>>>(
        Pws, Qws, Hin);
    scan_chunk_kernel<1><<<scan_blocks, blk, 4 * CLEN * 16 * 4, stream>>>(
        delta, u, xdbl, xz, A_log, D_param, nullptr, nullptr, Hin, y_bf);

    // 6) out = y @ out_proj_w^T   (bf16 MFMA)
    gemm_mfma_bt<<<dim3(D_MODEL / 128, M_ROWS / 128), blk, 0, stream>>>(
        y_bf, opw_bf, out, M_ROWS, D_MODEL, D_INNER);
}

// Round 4
// 495.718 us; speedup vs baseline: 4.0798x; 1.2052x over previous
//
#include <hip/hip_runtime.h>
#include <hip/hip_bf16.h>
#include <math.h>

#define D_MODEL 1024
#define D_STATE 16
#define D_CONV 4
#define D_INNER 2048
#define DT_RANK 64
#define L_SEQ 2048
#define N_BATCH 2
#define M_ROWS (N_BATCH * L_SEQ)   // 4096

#define N_CHUNK 32                 // chunks over L
#define CLEN (L_SEQ / N_CHUNK)     // 64 timesteps per chunk

typedef __attribute__((ext_vector_type(8))) __bf16 bf16x8;
typedef __attribute__((ext_vector_type(4))) float f32x4;

__device__ __forceinline__ unsigned short f2b(float f) {
    unsigned int u = __float_as_uint(f);
    unsigned int r = (u + 0x7fffu + ((u >> 16) & 1u)) >> 16;   // RNE
    return (unsigned short)r;
}

// addrspace casts for global_load_lds
#define AS1G(p) ((const __attribute__((address_space(1))) void*)(uintptr_t)(p))
#define AS3L(p) ((__attribute__((address_space(3))) void*)(unsigned int)(uintptr_t)(p))

// ---------------------------------------------------------------------------
// fp32 -> bf16 cast, float4 granularity
// ---------------------------------------------------------------------------
__global__ __launch_bounds__(256) void cvt_bf16_kernel(
    const float* __restrict__ src, unsigned short* __restrict__ dst, int n4)
{
    const int i = blockIdx.x * 256 + threadIdx.x;
    if (i < n4) {
        const float4 f = ((const float4*)src)[i];
        ushort4 o;
        o.x = f2b(f.x); o.y = f2b(f.y); o.z = f2b(f.z); o.w = f2b(f.w);
        ((ushort4*)dst)[i] = o;
    }
}

// ---------------------------------------------------------------------------
// bf16 MFMA GEMM (m97 structure): C[M,N] = A[M,K] * B[N,K]^T, fp32 out.
// ---------------------------------------------------------------------------
__global__ __launch_bounds__(256) void gemm_mfma_bt(
    const unsigned short* __restrict__ A, const unsigned short* __restrict__ B,
    float* __restrict__ C, int M, int N, int K)
{
    __shared__ unsigned short As[128 * 32];
    __shared__ unsigned short Bs[128 * 32];

    const int tid  = threadIdx.x;
    const int wave = tid >> 6;
    const int lane = tid & 63;
    const int row0 = blockIdx.y * 128;
    const int col0 = blockIdx.x * 128;
    const int wr = (wave >> 1) * 64;
    const int wc = (wave & 1) * 64;
    const int lm = lane & 15;
    const int kg = (lane >> 4) * 8;

    f32x4 acc[4][4];
    #pragma unroll
    for (int i = 0; i < 4; ++i)
        #pragma unroll
        for (int j = 0; j < 4; ++j)
            acc[i][j] = (f32x4){0.f, 0.f, 0.f, 0.f};

    const int c0 = tid;
    const int c1 = tid + 256;
    const int r0_ = c0 >> 2, kq0 = (c0 & 3) * 8;
    const int r1_ = c1 >> 2, kq1 = (c1 & 3) * 8;
    unsigned short* lA0 = As + wave * 512;
    unsigned short* lA1 = As + 2048 + wave * 512;
    unsigned short* lB0 = Bs + wave * 512;
    unsigned short* lB1 = Bs + 2048 + wave * 512;

    for (int k0 = 0; k0 < K; k0 += 32) {
        __syncthreads();
        __builtin_amdgcn_global_load_lds(AS1G(A + (size_t)(row0 + r0_) * K + k0 + kq0), AS3L(lA0), 16, 0, 0);
        __builtin_amdgcn_global_load_lds(AS1G(A + (size_t)(row0 + r1_) * K + k0 + kq1), AS3L(lA1), 16, 0, 0);
        __builtin_amdgcn_global_load_lds(AS1G(B + (size_t)(col0 + r0_) * K + k0 + kq0), AS3L(lB0), 16, 0, 0);
        __builtin_amdgcn_global_load_lds(AS1G(B + (size_t)(col0 + r1_) * K + k0 + kq1), AS3L(lB1), 16, 0, 0);
        __syncthreads();

        bf16x8 af[4], bf[4];
        #pragma unroll
        for (int i = 0; i < 4; ++i) {
            af[i] = *(const bf16x8*)&As[(wr + i * 16 + lm) * 32 + kg];
            bf[i] = *(const bf16x8*)&Bs[(wc + i * 16 + lm) * 32 + kg];
        }
        #pragma unroll
        for (int i = 0; i < 4; ++i)
            #pragma unroll
            for (int j = 0; j < 4; ++j)
                acc[i][j] = __builtin_amdgcn_mfma_f32_16x16x32_bf16(af[i], bf[j], acc[i][j], 0, 0, 0);
    }

    #pragma unroll
    for (int i = 0; i < 4; ++i) {
        const int r = row0 + wr + i * 16 + (lane >> 4) * 4;
        #pragma unroll
        for (int j = 0; j < 4; ++j) {
            const int cc = col0 + wc + j * 16 + lm;
            #pragma unroll
            for (int v = 0; v < 4; ++v)
                C[(size_t)(r + v) * N + cc] = acc[i][j][v];
        }
    }
}

// ---------------------------------------------------------------------------
// fp32 fallback GEMM (x_proj, dt_proj): C[M,N] = A[M,K]*B[N,K]^T
// ---------------------------------------------------------------------------
#define BK 16
#define LDS_PITCH 68

template <int MODE>
__global__ __launch_bounds__(256) void gemm_bt(
    const float* __restrict__ A, const float* __restrict__ B,
    float* __restrict__ C, const float* __restrict__ bias,
    int M, int N, int K, int lda, int ldb, int ldc)
{
    __shared__ float As[BK][LDS_PITCH];
    __shared__ float Bs[BK][LDS_PITCH];
    const int tid  = threadIdx.x;
    const int row0 = blockIdx.y * 64;
    const int col0 = blockIdx.x * 64;
    const int ar = tid >> 2;
    const int ak = (tid & 3) * 4;
    const int ty = tid >> 4;
    const int tx = tid & 15;

    float acc[4][4];
    #pragma unroll
    for (int i = 0; i < 4; ++i)
        #pragma unroll
        for (int j = 0; j < 4; ++j) acc[i][j] = 0.f;

    for (int k0 = 0; k0 < K; k0 += BK) {
        float4 av = *(const float4*)(A + (size_t)(row0 + ar) * lda + k0 + ak);
        float4 bv;
        const int gcol = col0 + ar;
        if (gcol < N) bv = *(const float4*)(B + (size_t)gcol * ldb + k0 + ak);
        else          bv = make_float4(0.f, 0.f, 0.f, 0.f);

        __syncthreads();
        As[ak + 0][ar] = av.x; As[ak + 1][ar] = av.y;
        As[ak + 2][ar] = av.z; As[ak + 3][ar] = av.w;
        Bs[ak + 0][ar] = bv.x; Bs[ak + 1][ar] = bv.y;
        Bs[ak + 2][ar] = bv.z; Bs[ak + 3][ar] = bv.w;
        __syncthreads();

        #pragma unroll
        for (int kk = 0; kk < BK; ++kk) {
            const float4 a4 = *(const float4*)&As[kk][ty * 4];
            const float4 b4 = *(const float4*)&Bs[kk][tx * 4];
            const float a[4] = {a4.x, a4.y, a4.z, a4.w};
            const float b[4] = {b4.x, b4.y, b4.z, b4.w};
            #pragma unroll
            for (int i = 0; i < 4; ++i)
                #pragma unroll
                for (int j = 0; j < 4; ++j)
                    acc[i][j] = fmaf(a[i], b[j], acc[i][j]);
        }
    }

    #pragma unroll
    for (int i = 0; i < 4; ++i) {
        const int r = row0 + ty * 4 + i;
        #pragma unroll
        for (int j = 0; j < 4; ++j) {
            const int c = col0 + tx * 4 + j;
            if (c < N) {
                float v = acc[i][j];
                if (MODE == 1) {
                    v += bias[c];
                    v = (v > 20.f) ? v : log1pf(__expf(v));
                }
                C[(size_t)r * ldc + c] = v;
            }
        }
    }
}

// ---------------------------------------------------------------------------
// Depthwise causal conv (width 4) + bias + SiLU.
// ---------------------------------------------------------------------------
__global__ __launch_bounds__(256) void conv_silu_kernel(
    const float* __restrict__ xz, const float* __restrict__ conv_w,
    const float* __restrict__ conv_b, float* __restrict__ u)
{
    const int idx = blockIdx.x * 256 + threadIdx.x;
    const int c  = idx & (D_INNER - 1);
    const int ml = idx >> 11;
    const int l  = ml & (L_SEQ - 1);
    float acc = conv_b[c];
    const float* w = conv_w + c * D_CONV;
    #pragma unroll
    for (int j = 0; j < D_CONV; ++j) {
        const int ll = l - (D_CONV - 1) + j;
        if (ll >= 0)
            acc = fmaf(xz[(size_t)(ml - (D_CONV - 1) + j) * (2 * D_INNER) + c], w[j], acc);
    }
    u[(size_t)ml * D_INNER + c] = acc / (1.f + __expf(-acc));
}

// ---------------------------------------------------------------------------
// Sequential-register selective scan.  One lane owns one d channel and all 16
// states in registers.  delta/u/z: coalesced per-step global loads (VMEM).
// B/C: wave-uniform -> scalar loads (SMEM).  No LDS, no cross-lane ops.
// Block = 256 threads = 256 d.  Grid = B * (D_INNER/256) * N_CHUNK.
// PHASE 0: P = prod dA, Q = local scan from 0.   PHASE 1: scan from Hin -> y.
// ---------------------------------------------------------------------------
template <int PHASE>
__global__ __launch_bounds__(256) void scan_seq_kernel(
    const float* __restrict__ delta, const float* __restrict__ u,
    const float* __restrict__ xdbl,  const float* __restrict__ xz,
    const float* __restrict__ A_log, const float* __restrict__ Dp,
    float* __restrict__ P, float* __restrict__ Q,
    const float* __restrict__ Hin, unsigned short* __restrict__ y)
{
    const int bid  = blockIdx.x;
    const int c    = bid & (N_CHUNK - 1);
    const int rest = bid >> 5;              // log2(N_CHUNK)=5
    const int b    = rest >> 3;             // 8 d-groups of 256
    const int dgrp = rest & 7;
    const int d    = dgrp * 256 + threadIdx.x;
    const int t0   = c * CLEN;

    // per-lane A coefficients: A = -exp(A_log[d][n])
    float nA[16];
    #pragma unroll
    for (int k = 0; k < 4; ++k) {
        const float4 a4 = *(const float4*)(A_log + (size_t)d * 16 + k * 4);
        nA[4 * k + 0] = -__expf(a4.x);
        nA[4 * k + 1] = -__expf(a4.y);
        nA[4 * k + 2] = -__expf(a4.z);
        nA[4 * k + 3] = -__expf(a4.w);
    }

    const size_t sbase = (((size_t)(b * N_CHUNK + c)) << 15) + ((size_t)d << 4);

    float h[16], Pacc[16];
    if (PHASE == 0) {
        #pragma unroll
        for (int n = 0; n < 16; ++n) { h[n] = 0.f; Pacc[n] = 1.f; }
    } else {
        #pragma unroll
        for (int k = 0; k < 4; ++k) {
            const float4 h4 = *(const float4*)(Hin + sbase + k * 4);
            h[4 * k + 0] = h4.x; h[4 * k + 1] = h4.y;
            h[4 * k + 2] = h4.z; h[4 * k + 3] = h4.w;
        }
    }
    const float Dd = (PHASE == 1) ? Dp[d] : 0.f;

    #pragma unroll 2
    for (int t = 0; t < CLEN; ++t) {
        const size_t m = (size_t)b * L_SEQ + t0 + t;
        const float dt_v = delta[m * D_INNER + d];
        const float u_v  = u[m * D_INNER + d];
        const float dtu  = dt_v * u_v;
        const float* sB = xdbl + m * 96 + DT_RANK;   // wave-uniform -> s_load
        const float* sC = sB + D_STATE;

        float v = u_v * Dd;
        #pragma unroll
        for (int n = 0; n < 16; ++n) {
            const float dA = __expf(dt_v * nA[n]);
            if (PHASE == 0) Pacc[n] *= dA;
            h[n] = fmaf(dA, h[n], dtu * sB[n]);
            if (PHASE == 1) v = fmaf(h[n], sC[n], v);
        }
        if (PHASE == 1) {
            const float z   = xz[m * (2 * D_INNER) + D_INNER + d];
            const float sig = 1.f / (1.f + __expf(-z));
            y[m * D_INNER + d] = f2b(v * z * sig);
        }
    }

    if (PHASE == 0) {
        #pragma unroll
        for (int k = 0; k < 4; ++k) {
            *(float4*)(P + sbase + k * 4) =
                make_float4(Pacc[4*k], Pacc[4*k+1], Pacc[4*k+2], Pacc[4*k+3]);
            *(float4*)(Q + sbase + k * 4) =
                make_float4(h[4*k], h[4*k+1], h[4*k+2], h[4*k+3]);
        }
    }
}

// ---------------------------------------------------------------------------
// Sequential chunk composition: h_in[c] for each (b,d,n).
// ---------------------------------------------------------------------------
__global__ __launch_bounds__(256) void scan_combine_kernel(
    const float* __restrict__ P, const float* __restrict__ Q,
    float* __restrict__ Hin)
{
    const int idx = blockIdx.x * 256 + threadIdx.x;
    const int b   = idx >> 15;
    const int dn  = idx & 32767;
    float h = 0.f;
    #pragma unroll
    for (int c = 0; c < N_CHUNK; ++c) {
        const size_t o = ((size_t)(b * N_CHUNK + c) << 15) + dn;
        Hin[o] = h;
        h = fmaf(P[o], h, Q[o]);
    }
}

// ---------------------------------------------------------------------------
// Launch
// ---------------------------------------------------------------------------
extern "C" void kernel_launch(void* const* d_in, const int* in_sizes, int n_in,
                              void* d_out, int out_size, void* d_ws, size_t ws_size,
                              hipStream_t stream)
{
    const float* hs        = (const float*)d_in[0];
    const float* in_proj_w = (const float*)d_in[1];
    const float* conv_w    = (const float*)d_in[2];
    const float* conv_b    = (const float*)d_in[3];
    const float* x_proj_w  = (const float*)d_in[4];
    const float* dt_proj_w = (const float*)d_in[5];
    const float* dt_proj_b = (const float*)d_in[6];
    const float* A_log     = (const float*)d_in[7];
    const float* D_param   = (const float*)d_in[8];
    const float* out_proj_w= (const float*)d_in[9];
    float* out = (float*)d_out;

    // workspace layout (fp32 part)
    float* xz    = (float*)d_ws;
    float* u     = xz    + (size_t)M_ROWS * (2 * D_INNER);
    float* xdbl  = u     + (size_t)M_ROWS * D_INNER;
    float* delta = xdbl  + (size_t)M_ROWS * 96;
    float* Pws   = delta + (size_t)M_ROWS * D_INNER;
    float* Qws   = Pws   + (size_t)N_BATCH * N_CHUNK * D_INNER * 16;
    float* Hin   = Qws   + (size_t)N_BATCH * N_CHUNK * D_INNER * 16;
    // bf16 part
    unsigned short* opw_bf = (unsigned short*)(Hin + (size_t)N_BATCH * N_CHUNK * D_INNER * 16);
    unsigned short* y_bf   = opw_bf + (size_t)D_MODEL * D_INNER;
    // hs_bf/ipw_bf alias the delta region (consumed before delta is written)
    unsigned short* hs_bf  = (unsigned short*)delta;
    unsigned short* ipw_bf = hs_bf + (size_t)M_ROWS * D_MODEL;

    const dim3 blk(256);

    // 0) fp32 -> bf16 casts
    cvt_bf16_kernel<<<(M_ROWS * D_MODEL / 4 + 255) / 256, blk, 0, stream>>>(
        hs, hs_bf, M_ROWS * D_MODEL / 4);
    cvt_bf16_kernel<<<(2 * D_INNER * D_MODEL / 4 + 255) / 256, blk, 0, stream>>>(
        in_proj_w, ipw_bf, 2 * D_INNER * D_MODEL / 4);
    cvt_bf16_kernel<<<(D_MODEL * D_INNER / 4 + 255) / 256, blk, 0, stream>>>(
        out_proj_w, opw_bf, D_MODEL * D_INNER / 4);

    // 1) xz = hs @ in_proj_w^T   (bf16 MFMA)
    gemm_mfma_bt<<<dim3((2 * D_INNER) / 128, M_ROWS / 128), blk, 0, stream>>>(
        hs_bf, ipw_bf, xz, M_ROWS, 2 * D_INNER, D_MODEL);

    // 2) u = silu(causal_conv(x) + conv_b)
    conv_silu_kernel<<<(M_ROWS * D_INNER) / 256, blk, 0, stream>>>(
        xz, conv_w, conv_b, u);

    // 3) x_dbl = u @ x_proj_w^T   (fp32)
    gemm_bt<0><<<dim3(2, 64), blk, 0, stream>>>(
        u, x_proj_w, xdbl, nullptr, M_ROWS, 96, D_INNER,
        D_INNER, D_INNER, 96);

    // 4) delta = softplus(dt @ dt_proj_w^T + dt_proj_b)   (fp32)
    gemm_bt<1><<<dim3(32, 64), blk, 0, stream>>>(
        xdbl, dt_proj_w, delta, dt_proj_b, M_ROWS, D_INNER, DT_RANK,
        96, DT_RANK, D_INNER);

    // 5) chunked selective scan (register-sequential, no LDS)
    const int scan_blocks = N_BATCH * (D_INNER / 256) * N_CHUNK;  // 512
    scan_seq_kernel<0><<<scan_blocks, blk, 0, stream>>>(
        delta, u, xdbl, xz, A_log, D_param, Pws, Qws, nullptr, nullptr);
    scan_combine_kernel<<<(N_BATCH * D_INNER * 16) / 256, blk, 0, stream>>>(
        Pws, Qws, Hin);
    scan_seq_kernel<1><<<scan_blocks, blk, 0, stream>>>(
        delta, u, xdbl, xz, A_log, D_param, nullptr, nullptr, Hin, y_bf);

    // 6) out = y @ out_proj_w^T   (bf16 MFMA)
    gemm_mfma_bt<<<dim3(D_MODEL / 128, M_ROWS / 128), blk, 0, stream>>>(
        y_bf, opw_bf, out, M_ROWS, D_MODEL, D_INNER);
}

// Round 5
// 395.321 us; speedup vs baseline: 5.1159x; 1.2540x over previous
//
#include <hip/hip_runtime.h>
#include <hip/hip_bf16.h>
#include <math.h>

#define D_MODEL 1024
#define D_STATE 16
#define D_CONV 4
#define D_INNER 2048
#define DT_RANK 64
#define L_SEQ 2048
#define N_BATCH 2
#define M_ROWS (N_BATCH * L_SEQ)   // 4096

#define N_CHUNK 32                 // chunks over L
#define CLEN (L_SEQ / N_CHUNK)     // 64 timesteps per chunk

#define XP_KSPLIT 8                // split-K factor for x_proj
#define XP_KLEN (D_INNER / XP_KSPLIT)  // 256

typedef __attribute__((ext_vector_type(8))) __bf16 bf16x8;
typedef __attribute__((ext_vector_type(4))) float f32x4;

__device__ __forceinline__ unsigned short f2b(float f) {
    unsigned int u = __float_as_uint(f);
    unsigned int r = (u + 0x7fffu + ((u >> 16) & 1u)) >> 16;   // RNE
    return (unsigned short)r;
}

// addrspace casts for global_load_lds
#define AS1G(p) ((const __attribute__((address_space(1))) void*)(uintptr_t)(p))
#define AS3L(p) ((__attribute__((address_space(3))) void*)(unsigned int)(uintptr_t)(p))

// ---------------------------------------------------------------------------
// fp32 -> bf16 cast, float4 granularity
// ---------------------------------------------------------------------------
__global__ __launch_bounds__(256) void cvt_bf16_kernel(
    const float* __restrict__ src, unsigned short* __restrict__ dst, int n4)
{
    const int i = blockIdx.x * 256 + threadIdx.x;
    if (i < n4) {
        const float4 f = ((const float4*)src)[i];
        ushort4 o;
        o.x = f2b(f.x); o.y = f2b(f.y); o.z = f2b(f.z); o.w = f2b(f.w);
        ((ushort4*)dst)[i] = o;
    }
}

// cast x_proj_w (96 x 2048) -> bf16 padded to 128 x 2048 (rows 96..127 zero)
__global__ __launch_bounds__(256) void cvt_pad_xpw_kernel(
    const float* __restrict__ src, unsigned short* __restrict__ dst)
{
    const int i = blockIdx.x * 256 + threadIdx.x;      // over 128*2048/4
    if (i >= 128 * D_INNER / 4) return;
    const int row = (i * 4) >> 11;                      // /2048
    ushort4 o;
    if (row < 96) {
        const float4 f = ((const float4*)src)[i];
        o.x = f2b(f.x); o.y = f2b(f.y); o.z = f2b(f.z); o.w = f2b(f.w);
    } else {
        o.x = o.y = o.z = o.w = 0;
    }
    ((ushort4*)dst)[i] = o;
}

// ---------------------------------------------------------------------------
// bf16 MFMA GEMM (m97 structure): C[M,N] = A[M,K]*B[N,K]^T, fp32 out.
// Split-K: blockIdx.z selects K-chunk [z*k_len, (z+1)*k_len); C offset by
// z*M*N (partials).  Full GEMM: gridDim.z=1, k_len=K.
// ---------------------------------------------------------------------------
__global__ __launch_bounds__(256) void gemm_mfma_bt(
    const unsigned short* __restrict__ A, const unsigned short* __restrict__ B,
    float* __restrict__ C, int M, int N, int K, int k_len)
{
    __shared__ unsigned short As[128 * 32];
    __shared__ unsigned short Bs[128 * 32];

    const int tid  = threadIdx.x;
    const int wave = tid >> 6;
    const int lane = tid & 63;
    const int row0 = blockIdx.y * 128;
    const int col0 = blockIdx.x * 128;
    const int kbeg = blockIdx.z * k_len;
    C += (size_t)blockIdx.z * M * N;
    const int wr = (wave >> 1) * 64;
    const int wc = (wave & 1) * 64;
    const int lm = lane & 15;
    const int kg = (lane >> 4) * 8;

    f32x4 acc[4][4];
    #pragma unroll
    for (int i = 0; i < 4; ++i)
        #pragma unroll
        for (int j = 0; j < 4; ++j)
            acc[i][j] = (f32x4){0.f, 0.f, 0.f, 0.f};

    const int c0 = tid;
    const int c1 = tid + 256;
    const int r0_ = c0 >> 2, kq0 = (c0 & 3) * 8;
    const int r1_ = c1 >> 2, kq1 = (c1 & 3) * 8;
    unsigned short* lA0 = As + wave * 512;
    unsigned short* lA1 = As + 2048 + wave * 512;
    unsigned short* lB0 = Bs + wave * 512;
    unsigned short* lB1 = Bs + 2048 + wave * 512;

    for (int k0 = kbeg; k0 < kbeg + k_len; k0 += 32) {
        __syncthreads();
        __builtin_amdgcn_global_load_lds(AS1G(A + (size_t)(row0 + r0_) * K + k0 + kq0), AS3L(lA0), 16, 0, 0);
        __builtin_amdgcn_global_load_lds(AS1G(A + (size_t)(row0 + r1_) * K + k0 + kq1), AS3L(lA1), 16, 0, 0);
        __builtin_amdgcn_global_load_lds(AS1G(B + (size_t)(col0 + r0_) * K + k0 + kq0), AS3L(lB0), 16, 0, 0);
        __builtin_amdgcn_global_load_lds(AS1G(B + (size_t)(col0 + r1_) * K + k0 + kq1), AS3L(lB1), 16, 0, 0);
        __syncthreads();

        bf16x8 af[4], bf[4];
        #pragma unroll
        for (int i = 0; i < 4; ++i) {
            af[i] = *(const bf16x8*)&As[(wr + i * 16 + lm) * 32 + kg];
            bf[i] = *(const bf16x8*)&Bs[(wc + i * 16 + lm) * 32 + kg];
        }
        #pragma unroll
        for (int i = 0; i < 4; ++i)
            #pragma unroll
            for (int j = 0; j < 4; ++j)
                acc[i][j] = __builtin_amdgcn_mfma_f32_16x16x32_bf16(af[i], bf[j], acc[i][j], 0, 0, 0);
    }

    #pragma unroll
    for (int i = 0; i < 4; ++i) {
        const int r = row0 + wr + i * 16 + (lane >> 4) * 4;
        #pragma unroll
        for (int j = 0; j < 4; ++j) {
            const int cc = col0 + wc + j * 16 + lm;
            #pragma unroll
            for (int v = 0; v < 4; ++v)
                C[(size_t)(r + v) * N + cc] = acc[i][j][v];
        }
    }
}

// reduce split-K partials [XP_KSPLIT][M][128] -> xdbl [M][96]
__global__ __launch_bounds__(256) void xproj_reduce_kernel(
    const float* __restrict__ part, float* __restrict__ xdbl)
{
    const int i = blockIdx.x * 256 + threadIdx.x;   // over M * 24
    if (i >= M_ROWS * 24) return;
    const int m  = i / 24;
    const int j4 = (i - m * 24) * 4;
    f32x4 s = *(const f32x4*)(part + (size_t)m * 128 + j4);
    #pragma unroll
    for (int ks = 1; ks < XP_KSPLIT; ++ks)
        s += *(const f32x4*)(part + (size_t)ks * M_ROWS * 128 + (size_t)m * 128 + j4);
    *(f32x4*)(xdbl + (size_t)m * 96 + j4) = s;
}

// ---------------------------------------------------------------------------
// fp32 fallback GEMM (dt_proj): C[M,N] = A[M,K]*B[N,K]^T
// ---------------------------------------------------------------------------
#define BK 16
#define LDS_PITCH 68

template <int MODE>
__global__ __launch_bounds__(256) void gemm_bt(
    const float* __restrict__ A, const float* __restrict__ B,
    float* __restrict__ C, const float* __restrict__ bias,
    int M, int N, int K, int lda, int ldb, int ldc)
{
    __shared__ float As[BK][LDS_PITCH];
    __shared__ float Bs[BK][LDS_PITCH];
    const int tid  = threadIdx.x;
    const int row0 = blockIdx.y * 64;
    const int col0 = blockIdx.x * 64;
    const int ar = tid >> 2;
    const int ak = (tid & 3) * 4;
    const int ty = tid >> 4;
    const int tx = tid & 15;

    float acc[4][4];
    #pragma unroll
    for (int i = 0; i < 4; ++i)
        #pragma unroll
        for (int j = 0; j < 4; ++j) acc[i][j] = 0.f;

    for (int k0 = 0; k0 < K; k0 += BK) {
        float4 av = *(const float4*)(A + (size_t)(row0 + ar) * lda + k0 + ak);
        float4 bv;
        const int gcol = col0 + ar;
        if (gcol < N) bv = *(const float4*)(B + (size_t)gcol * ldb + k0 + ak);
        else          bv = make_float4(0.f, 0.f, 0.f, 0.f);

        __syncthreads();
        As[ak + 0][ar] = av.x; As[ak + 1][ar] = av.y;
        As[ak + 2][ar] = av.z; As[ak + 3][ar] = av.w;
        Bs[ak + 0][ar] = bv.x; Bs[ak + 1][ar] = bv.y;
        Bs[ak + 2][ar] = bv.z; Bs[ak + 3][ar] = bv.w;
        __syncthreads();

        #pragma unroll
        for (int kk = 0; kk < BK; ++kk) {
            const float4 a4 = *(const float4*)&As[kk][ty * 4];
            const float4 b4 = *(const float4*)&Bs[kk][tx * 4];
            const float a[4] = {a4.x, a4.y, a4.z, a4.w};
            const float b[4] = {b4.x, b4.y, b4.z, b4.w};
            #pragma unroll
            for (int i = 0; i < 4; ++i)
                #pragma unroll
                for (int j = 0; j < 4; ++j)
                    acc[i][j] = fmaf(a[i], b[j], acc[i][j]);
        }
    }

    #pragma unroll
    for (int i = 0; i < 4; ++i) {
        const int r = row0 + ty * 4 + i;
        #pragma unroll
        for (int j = 0; j < 4; ++j) {
            const int c = col0 + tx * 4 + j;
            if (c < N) {
                float v = acc[i][j];
                if (MODE == 1) {
                    v += bias[c];
                    v = (v > 20.f) ? v : log1pf(__expf(v));
                }
                C[(size_t)r * ldc + c] = v;
            }
        }
    }
}

// ---------------------------------------------------------------------------
// Depthwise causal conv (width 4) + bias + SiLU.  Writes u (fp32) + u_bf.
// ---------------------------------------------------------------------------
__global__ __launch_bounds__(256) void conv_silu_kernel(
    const float* __restrict__ xz, const float* __restrict__ conv_w,
    const float* __restrict__ conv_b, float* __restrict__ u,
    unsigned short* __restrict__ u_bf)
{
    const int idx = blockIdx.x * 256 + threadIdx.x;
    const int c  = idx & (D_INNER - 1);
    const int ml = idx >> 11;
    const int l  = ml & (L_SEQ - 1);
    float acc = conv_b[c];
    const float* w = conv_w + c * D_CONV;
    #pragma unroll
    for (int j = 0; j < D_CONV; ++j) {
        const int ll = l - (D_CONV - 1) + j;
        if (ll >= 0)
            acc = fmaf(xz[(size_t)(ml - (D_CONV - 1) + j) * (2 * D_INNER) + c], w[j], acc);
    }
    const float uv = acc / (1.f + __expf(-acc));
    u[(size_t)ml * D_INNER + c] = uv;
    u_bf[(size_t)ml * D_INNER + c] = f2b(uv);
}

// ---------------------------------------------------------------------------
// Sequential-register selective scan (see round 3).
// ---------------------------------------------------------------------------
template <int PHASE>
__global__ __launch_bounds__(256) void scan_seq_kernel(
    const float* __restrict__ delta, const float* __restrict__ u,
    const float* __restrict__ xdbl,  const float* __restrict__ xz,
    const float* __restrict__ A_log, const float* __restrict__ Dp,
    float* __restrict__ P, float* __restrict__ Q,
    const float* __restrict__ Hin, unsigned short* __restrict__ y)
{
    const int bid  = blockIdx.x;
    const int c    = bid & (N_CHUNK - 1);
    const int rest = bid >> 5;
    const int b    = rest >> 3;
    const int dgrp = rest & 7;
    const int d    = dgrp * 256 + threadIdx.x;
    const int t0   = c * CLEN;

    float nA[16];
    #pragma unroll
    for (int k = 0; k < 4; ++k) {
        const float4 a4 = *(const float4*)(A_log + (size_t)d * 16 + k * 4);
        nA[4 * k + 0] = -__expf(a4.x);
        nA[4 * k + 1] = -__expf(a4.y);
        nA[4 * k + 2] = -__expf(a4.z);
        nA[4 * k + 3] = -__expf(a4.w);
    }

    const size_t sbase = (((size_t)(b * N_CHUNK + c)) << 15) + ((size_t)d << 4);

    float h[16], Pacc[16];
    if (PHASE == 0) {
        #pragma unroll
        for (int n = 0; n < 16; ++n) { h[n] = 0.f; Pacc[n] = 1.f; }
    } else {
        #pragma unroll
        for (int k = 0; k < 4; ++k) {
            const float4 h4 = *(const float4*)(Hin + sbase + k * 4);
            h[4 * k + 0] = h4.x; h[4 * k + 1] = h4.y;
            h[4 * k + 2] = h4.z; h[4 * k + 3] = h4.w;
        }
    }
    const float Dd = (PHASE == 1) ? Dp[d] : 0.f;

    #pragma unroll 2
    for (int t = 0; t < CLEN; ++t) {
        const size_t m = (size_t)b * L_SEQ + t0 + t;
        const float dt_v = delta[m * D_INNER + d];
        const float u_v  = u[m * D_INNER + d];
        const float dtu  = dt_v * u_v;
        const float* sB = xdbl + m * 96 + DT_RANK;   // wave-uniform -> s_load
        const float* sC = sB + D_STATE;

        float v = u_v * Dd;
        #pragma unroll
        for (int n = 0; n < 16; ++n) {
            const float dA = __expf(dt_v * nA[n]);
            if (PHASE == 0) Pacc[n] *= dA;
            h[n] = fmaf(dA, h[n], dtu * sB[n]);
            if (PHASE == 1) v = fmaf(h[n], sC[n], v);
        }
        if (PHASE == 1) {
            const float z   = xz[m * (2 * D_INNER) + D_INNER + d];
            const float sig = 1.f / (1.f + __expf(-z));
            y[m * D_INNER + d] = f2b(v * z * sig);
        }
    }

    if (PHASE == 0) {
        #pragma unroll
        for (int k = 0; k < 4; ++k) {
            *(float4*)(P + sbase + k * 4) =
                make_float4(Pacc[4*k], Pacc[4*k+1], Pacc[4*k+2], Pacc[4*k+3]);
            *(float4*)(Q + sbase + k * 4) =
                make_float4(h[4*k], h[4*k+1], h[4*k+2], h[4*k+3]);
        }
    }
}

// ---------------------------------------------------------------------------
// Sequential chunk composition: h_in[c] for each (b,d,n).
// ---------------------------------------------------------------------------
__global__ __launch_bounds__(256) void scan_combine_kernel(
    const float* __restrict__ P, const float* __restrict__ Q,
    float* __restrict__ Hin)
{
    const int idx = blockIdx.x * 256 + threadIdx.x;
    const int b   = idx >> 15;
    const int dn  = idx & 32767;
    float h = 0.f;
    #pragma unroll
    for (int c = 0; c < N_CHUNK; ++c) {
        const size_t o = ((size_t)(b * N_CHUNK + c) << 15) + dn;
        Hin[o] = h;
        h = fmaf(P[o], h, Q[o]);
    }
}

// ---------------------------------------------------------------------------
// Launch
// ---------------------------------------------------------------------------
extern "C" void kernel_launch(void* const* d_in, const int* in_sizes, int n_in,
                              void* d_out, int out_size, void* d_ws, size_t ws_size,
                              hipStream_t stream)
{
    const float* hs        = (const float*)d_in[0];
    const float* in_proj_w = (const float*)d_in[1];
    const float* conv_w    = (const float*)d_in[2];
    const float* conv_b    = (const float*)d_in[3];
    const float* x_proj_w  = (const float*)d_in[4];
    const float* dt_proj_w = (const float*)d_in[5];
    const float* dt_proj_b = (const float*)d_in[6];
    const float* A_log     = (const float*)d_in[7];
    const float* D_param   = (const float*)d_in[8];
    const float* out_proj_w= (const float*)d_in[9];
    float* out = (float*)d_out;

    // workspace layout (fp32 part)
    float* xz    = (float*)d_ws;                             // 4096*4096 f
    float* u     = xz    + (size_t)M_ROWS * (2 * D_INNER);   // 4096*2048 f
    float* xdbl  = u     + (size_t)M_ROWS * D_INNER;         // 4096*96 f
    float* delta = xdbl  + (size_t)M_ROWS * 96;              // 4096*2048 f
    float* Pws   = delta + (size_t)M_ROWS * D_INNER;
    float* Qws   = Pws   + (size_t)N_BATCH * N_CHUNK * D_INNER * 16;
    float* Hin   = Qws   + (size_t)N_BATCH * N_CHUNK * D_INNER * 16;
    // bf16 part
    unsigned short* opw_bf = (unsigned short*)(Hin + (size_t)N_BATCH * N_CHUNK * D_INNER * 16);
    unsigned short* y_bf   = opw_bf + (size_t)D_MODEL * D_INNER;
    unsigned short* xpw_bf = y_bf   + (size_t)M_ROWS * D_INNER;   // 128*2048 bf16
    // aliases inside the delta region (all dead before dt_proj writes delta):
    //   [0 .. 16.8MB) : hs_bf (8.4MB) + ipw_bf (8.4MB)   — live until in_proj
    //   [16.8 .. 33.5MB): u_bf (16.8MB)                  — live until x_proj
    unsigned short* hs_bf  = (unsigned short*)delta;
    unsigned short* ipw_bf = hs_bf + (size_t)M_ROWS * D_MODEL;
    unsigned short* u_bf   = ipw_bf + (size_t)2 * D_INNER * D_MODEL;
    // split-K partials alias y_bf (dead until scan phase1): [8][4096][128] f32
    float* xp_part = (float*)y_bf;

    const dim3 blk(256);

    // 0) fp32 -> bf16 casts
    cvt_bf16_kernel<<<(M_ROWS * D_MODEL / 4 + 255) / 256, blk, 0, stream>>>(
        hs, hs_bf, M_ROWS * D_MODEL / 4);
    cvt_bf16_kernel<<<(2 * D_INNER * D_MODEL / 4 + 255) / 256, blk, 0, stream>>>(
        in_proj_w, ipw_bf, 2 * D_INNER * D_MODEL / 4);
    cvt_bf16_kernel<<<(D_MODEL * D_INNER / 4 + 255) / 256, blk, 0, stream>>>(
        out_proj_w, opw_bf, D_MODEL * D_INNER / 4);
    cvt_pad_xpw_kernel<<<(128 * D_INNER / 4 + 255) / 256, blk, 0, stream>>>(
        x_proj_w, xpw_bf);

    // 1) xz = hs @ in_proj_w^T   (bf16 MFMA)
    gemm_mfma_bt<<<dim3((2 * D_INNER) / 128, M_ROWS / 128, 1), blk, 0, stream>>>(
        hs_bf, ipw_bf, xz, M_ROWS, 2 * D_INNER, D_MODEL, D_MODEL);

    // 2) u = silu(causal_conv(x) + conv_b)  (+ bf16 copy)
    conv_silu_kernel<<<(M_ROWS * D_INNER) / 256, blk, 0, stream>>>(
        xz, conv_w, conv_b, u, u_bf);

    // 3) x_dbl = u @ x_proj_w^T   (bf16 MFMA, split-K=8, padded N=128)
    gemm_mfma_bt<<<dim3(1, M_ROWS / 128, XP_KSPLIT), blk, 0, stream>>>(
        u_bf, xpw_bf, xp_part, M_ROWS, 128, D_INNER, XP_KLEN);
    xproj_reduce_kernel<<<(M_ROWS * 24 + 255) / 256, blk, 0, stream>>>(
        xp_part, xdbl);

    // 4) delta = softplus(dt @ dt_proj_w^T + dt_proj_b)   (fp32)
    gemm_bt<1><<<dim3(32, 64), blk, 0, stream>>>(
        xdbl, dt_proj_w, delta, dt_proj_b, M_ROWS, D_INNER, DT_RANK,
        96, DT_RANK, D_INNER);

    // 5) chunked selective scan (register-sequential, no LDS)
    const int scan_blocks = N_BATCH * (D_INNER / 256) * N_CHUNK;  // 512
    scan_seq_kernel<0><<<scan_blocks, blk, 0, stream>>>(
        delta, u, xdbl, xz, A_log, D_param, Pws, Qws, nullptr, nullptr);
    scan_combine_kernel<<<(N_BATCH * D_INNER * 16) / 256, blk, 0, stream>>>(
        Pws, Qws, Hin);
    scan_seq_kernel<1><<<scan_blocks, blk, 0, stream>>>(
        delta, u, xdbl, xz, A_log, D_param, nullptr, nullptr, Hin, y_bf);

    // 6) out = y @ out_proj_w^T   (bf16 MFMA)
    gemm_mfma_bt<<<dim3(D_MODEL / 128, M_ROWS / 128, 1), blk, 0, stream>>>(
        y_bf, opw_bf, out, M_ROWS, D_MODEL, D_INNER, D_INNER);
}

// Round 6
// 377.140 us; speedup vs baseline: 5.3625x; 1.0482x over previous
//
#include <hip/hip_runtime.h>
#include <hip/hip_bf16.h>
#include <math.h>

#define D_MODEL 1024
#define D_STATE 16
#define D_CONV 4
#define D_INNER 2048
#define DT_RANK 64
#define L_SEQ 2048
#define N_BATCH 2
#define M_ROWS (N_BATCH * L_SEQ)   // 4096

#define N_CHUNK 32                 // chunks over L
#define CLEN (L_SEQ / N_CHUNK)     // 64 timesteps per chunk

#define XP_KSPLIT 8                // split-K factor for x_proj
#define XP_KLEN (D_INNER / XP_KSPLIT)  // 256
#define OP_KSPLIT 2                // split-K factor for out_proj
#define OP_KLEN (D_INNER / OP_KSPLIT)  // 1024

typedef __attribute__((ext_vector_type(8))) __bf16 bf16x8;
typedef __attribute__((ext_vector_type(4))) float f32x4;

__device__ __forceinline__ unsigned short f2b(float f) {
    unsigned int u = __float_as_uint(f);
    unsigned int r = (u + 0x7fffu + ((u >> 16) & 1u)) >> 16;   // RNE
    return (unsigned short)r;
}
__device__ __forceinline__ float b2f(unsigned short s) {
    return __uint_as_float((unsigned int)s << 16);
}

// addrspace casts for global_load_lds
#define AS1G(p) ((const __attribute__((address_space(1))) void*)(uintptr_t)(p))
#define AS3L(p) ((__attribute__((address_space(3))) void*)(unsigned int)(uintptr_t)(p))

// ---------------------------------------------------------------------------
// fp32 -> bf16 cast, float4 granularity
// ---------------------------------------------------------------------------
__global__ __launch_bounds__(256) void cvt_bf16_kernel(
    const float* __restrict__ src, unsigned short* __restrict__ dst, int n4)
{
    const int i = blockIdx.x * 256 + threadIdx.x;
    if (i < n4) {
        const float4 f = ((const float4*)src)[i];
        ushort4 o;
        o.x = f2b(f.x); o.y = f2b(f.y); o.z = f2b(f.z); o.w = f2b(f.w);
        ((ushort4*)dst)[i] = o;
    }
}

// cast x_proj_w (96 x 2048) -> bf16 padded to 128 x 2048 (rows 96..127 zero)
__global__ __launch_bounds__(256) void cvt_pad_xpw_kernel(
    const float* __restrict__ src, unsigned short* __restrict__ dst)
{
    const int i = blockIdx.x * 256 + threadIdx.x;      // over 128*2048/4
    if (i >= 128 * D_INNER / 4) return;
    const int row = (i * 4) >> 11;                      // /2048
    ushort4 o;
    if (row < 96) {
        const float4 f = ((const float4*)src)[i];
        o.x = f2b(f.x); o.y = f2b(f.y); o.z = f2b(f.z); o.w = f2b(f.w);
    } else {
        o.x = o.y = o.z = o.w = 0;
    }
    ((ushort4*)dst)[i] = o;
}

// ---------------------------------------------------------------------------
// bf16 MFMA GEMM (m97 structure): C[M,N] = A[M,K]*B[N,K]^T, fp32 out.
// Split-K: blockIdx.z selects K-chunk [z*k_len,(z+1)*k_len), C += z*M*N.
// MODE 0: plain.  MODE 1: softplus(acc + bias[col]).
// ---------------------------------------------------------------------------
template <int MODE>
__global__ __launch_bounds__(256) void gemm_mfma_bt(
    const unsigned short* __restrict__ A, const unsigned short* __restrict__ B,
    float* __restrict__ C, const float* __restrict__ bias,
    int M, int N, int K, int k_len)
{
    __shared__ unsigned short As[128 * 32];
    __shared__ unsigned short Bs[128 * 32];

    const int tid  = threadIdx.x;
    const int wave = tid >> 6;
    const int lane = tid & 63;
    const int row0 = blockIdx.y * 128;
    const int col0 = blockIdx.x * 128;
    const int kbeg = blockIdx.z * k_len;
    C += (size_t)blockIdx.z * M * N;
    const int wr = (wave >> 1) * 64;
    const int wc = (wave & 1) * 64;
    const int lm = lane & 15;
    const int kg = (lane >> 4) * 8;

    f32x4 acc[4][4];
    #pragma unroll
    for (int i = 0; i < 4; ++i)
        #pragma unroll
        for (int j = 0; j < 4; ++j)
            acc[i][j] = (f32x4){0.f, 0.f, 0.f, 0.f};

    const int c0 = tid;
    const int c1 = tid + 256;
    const int r0_ = c0 >> 2, kq0 = (c0 & 3) * 8;
    const int r1_ = c1 >> 2, kq1 = (c1 & 3) * 8;
    unsigned short* lA0 = As + wave * 512;
    unsigned short* lA1 = As + 2048 + wave * 512;
    unsigned short* lB0 = Bs + wave * 512;
    unsigned short* lB1 = Bs + 2048 + wave * 512;

    for (int k0 = kbeg; k0 < kbeg + k_len; k0 += 32) {
        __syncthreads();
        __builtin_amdgcn_global_load_lds(AS1G(A + (size_t)(row0 + r0_) * K + k0 + kq0), AS3L(lA0), 16, 0, 0);
        __builtin_amdgcn_global_load_lds(AS1G(A + (size_t)(row0 + r1_) * K + k0 + kq1), AS3L(lA1), 16, 0, 0);
        __builtin_amdgcn_global_load_lds(AS1G(B + (size_t)(col0 + r0_) * K + k0 + kq0), AS3L(lB0), 16, 0, 0);
        __builtin_amdgcn_global_load_lds(AS1G(B + (size_t)(col0 + r1_) * K + k0 + kq1), AS3L(lB1), 16, 0, 0);
        __syncthreads();

        bf16x8 af[4], bf[4];
        #pragma unroll
        for (int i = 0; i < 4; ++i) {
            af[i] = *(const bf16x8*)&As[(wr + i * 16 + lm) * 32 + kg];
            bf[i] = *(const bf16x8*)&Bs[(wc + i * 16 + lm) * 32 + kg];
        }
        #pragma unroll
        for (int i = 0; i < 4; ++i)
            #pragma unroll
            for (int j = 0; j < 4; ++j)
                acc[i][j] = __builtin_amdgcn_mfma_f32_16x16x32_bf16(af[i], bf[j], acc[i][j], 0, 0, 0);
    }

    // C/D mapping: col = lane&15, row = (lane>>4)*4 + reg
    #pragma unroll
    for (int j = 0; j < 4; ++j) {
        const int cc = col0 + wc + j * 16 + lm;
        const float bv = (MODE == 1) ? bias[cc] : 0.f;
        #pragma unroll
        for (int i = 0; i < 4; ++i) {
            const int r = row0 + wr + i * 16 + (lane >> 4) * 4;
            #pragma unroll
            for (int v = 0; v < 4; ++v) {
                float val = acc[i][j][v];
                if (MODE == 1) {
                    val += bv;
                    val = (val > 20.f) ? val : log1pf(__expf(val));
                }
                C[(size_t)(r + v) * N + cc] = val;
            }
        }
    }
}

// reduce x_proj split-K partials [XP_KSPLIT][M][128] -> xdbl [M][96] fp32
// and dt_bf [M][64] bf16 (columns 0..63).
__global__ __launch_bounds__(256) void xproj_reduce_kernel(
    const float* __restrict__ part, float* __restrict__ xdbl,
    unsigned short* __restrict__ dt_bf)
{
    const int i = blockIdx.x * 256 + threadIdx.x;   // over M * 24
    if (i >= M_ROWS * 24) return;
    const int m  = i / 24;
    const int j4 = (i - m * 24) * 4;
    f32x4 s = *(const f32x4*)(part + (size_t)m * 128 + j4);
    #pragma unroll
    for (int ks = 1; ks < XP_KSPLIT; ++ks)
        s += *(const f32x4*)(part + (size_t)ks * M_ROWS * 128 + (size_t)m * 128 + j4);
    *(f32x4*)(xdbl + (size_t)m * 96 + j4) = s;
    if (j4 < DT_RANK) {
        ushort4 o;
        o.x = f2b(s.x); o.y = f2b(s.y); o.z = f2b(s.z); o.w = f2b(s.w);
        *(ushort4*)(dt_bf + (size_t)m * DT_RANK + j4) = o;
    }
}

// reduce out_proj split-K partials [OP_KSPLIT][M][D_MODEL] -> out
__global__ __launch_bounds__(256) void oproj_reduce_kernel(
    const float* __restrict__ part, float* __restrict__ out)
{
    const int i = blockIdx.x * 256 + threadIdx.x;   // over M*D_MODEL/4
    if (i >= M_ROWS * D_MODEL / 4) return;
    f32x4 s = ((const f32x4*)part)[i];
    #pragma unroll
    for (int ks = 1; ks < OP_KSPLIT; ++ks)
        s += ((const f32x4*)part)[(size_t)ks * (M_ROWS * D_MODEL / 4) + i];
    ((f32x4*)out)[i] = s;
}

// ---------------------------------------------------------------------------
// Depthwise causal conv (width 4) + bias + SiLU.  Writes u in bf16 only.
// ---------------------------------------------------------------------------
__global__ __launch_bounds__(256) void conv_silu_kernel(
    const float* __restrict__ xz, const float* __restrict__ conv_w,
    const float* __restrict__ conv_b, unsigned short* __restrict__ u_bf)
{
    const int idx = blockIdx.x * 256 + threadIdx.x;
    const int c  = idx & (D_INNER - 1);
    const int ml = idx >> 11;
    const int l  = ml & (L_SEQ - 1);
    float acc = conv_b[c];
    const float* w = conv_w + c * D_CONV;
    #pragma unroll
    for (int j = 0; j < D_CONV; ++j) {
        const int ll = l - (D_CONV - 1) + j;
        if (ll >= 0)
            acc = fmaf(xz[(size_t)(ml - (D_CONV - 1) + j) * (2 * D_INNER) + c], w[j], acc);
    }
    const float uv = acc / (1.f + __expf(-acc));
    u_bf[(size_t)ml * D_INNER + c] = f2b(uv);
}

// ---------------------------------------------------------------------------
// Sequential-register selective scan.  One lane owns one d channel and all 16
// states in registers.  delta: fp32; u: bf16; B/C: wave-uniform s_loads.
// ---------------------------------------------------------------------------
template <int PHASE>
__global__ __launch_bounds__(256) void scan_seq_kernel(
    const float* __restrict__ delta, const unsigned short* __restrict__ u_bf,
    const float* __restrict__ xdbl,  const float* __restrict__ xz,
    const float* __restrict__ A_log, const float* __restrict__ Dp,
    float* __restrict__ P, float* __restrict__ Q,
    const float* __restrict__ Hin, unsigned short* __restrict__ y)
{
    const int bid  = blockIdx.x;
    const int c    = bid & (N_CHUNK - 1);
    const int rest = bid >> 5;
    const int b    = rest >> 3;
    const int dgrp = rest & 7;
    const int d    = dgrp * 256 + threadIdx.x;
    const int t0   = c * CLEN;

    float nA[16];
    #pragma unroll
    for (int k = 0; k < 4; ++k) {
        const float4 a4 = *(const float4*)(A_log + (size_t)d * 16 + k * 4);
        nA[4 * k + 0] = -__expf(a4.x);
        nA[4 * k + 1] = -__expf(a4.y);
        nA[4 * k + 2] = -__expf(a4.z);
        nA[4 * k + 3] = -__expf(a4.w);
    }

    const size_t sbase = (((size_t)(b * N_CHUNK + c)) << 15) + ((size_t)d << 4);

    float h[16], Pacc[16];
    if (PHASE == 0) {
        #pragma unroll
        for (int n = 0; n < 16; ++n) { h[n] = 0.f; Pacc[n] = 1.f; }
    } else {
        #pragma unroll
        for (int k = 0; k < 4; ++k) {
            const float4 h4 = *(const float4*)(Hin + sbase + k * 4);
            h[4 * k + 0] = h4.x; h[4 * k + 1] = h4.y;
            h[4 * k + 2] = h4.z; h[4 * k + 3] = h4.w;
        }
    }
    const float Dd = (PHASE == 1) ? Dp[d] : 0.f;

    #pragma unroll 2
    for (int t = 0; t < CLEN; ++t) {
        const size_t m = (size_t)b * L_SEQ + t0 + t;
        const float dt_v = delta[m * D_INNER + d];
        const float u_v  = b2f(u_bf[m * D_INNER + d]);
        const float dtu  = dt_v * u_v;
        const float* sB = xdbl + m * 96 + DT_RANK;   // wave-uniform -> s_load
        const float* sC = sB + D_STATE;

        float v = u_v * Dd;
        #pragma unroll
        for (int n = 0; n < 16; ++n) {
            const float dA = __expf(dt_v * nA[n]);
            if (PHASE == 0) Pacc[n] *= dA;
            h[n] = fmaf(dA, h[n], dtu * sB[n]);
            if (PHASE == 1) v = fmaf(h[n], sC[n], v);
        }
        if (PHASE == 1) {
            const float z   = xz[m * (2 * D_INNER) + D_INNER + d];
            const float sig = 1.f / (1.f + __expf(-z));
            y[m * D_INNER + d] = f2b(v * z * sig);
        }
    }

    if (PHASE == 0) {
        #pragma unroll
        for (int k = 0; k < 4; ++k) {
            *(float4*)(P + sbase + k * 4) =
                make_float4(Pacc[4*k], Pacc[4*k+1], Pacc[4*k+2], Pacc[4*k+3]);
            *(float4*)(Q + sbase + k * 4) =
                make_float4(h[4*k], h[4*k+1], h[4*k+2], h[4*k+3]);
        }
    }
}

// ---------------------------------------------------------------------------
// Sequential chunk composition: h_in[c] for each (b,d,n).
// ---------------------------------------------------------------------------
__global__ __launch_bounds__(256) void scan_combine_kernel(
    const float* __restrict__ P, const float* __restrict__ Q,
    float* __restrict__ Hin)
{
    const int idx = blockIdx.x * 256 + threadIdx.x;
    const int b   = idx >> 15;
    const int dn  = idx & 32767;
    float h = 0.f;
    #pragma unroll
    for (int c = 0; c < N_CHUNK; ++c) {
        const size_t o = ((size_t)(b * N_CHUNK + c) << 15) + dn;
        Hin[o] = h;
        h = fmaf(P[o], h, Q[o]);
    }
}

// ---------------------------------------------------------------------------
// Launch
// ---------------------------------------------------------------------------
extern "C" void kernel_launch(void* const* d_in, const int* in_sizes, int n_in,
                              void* d_out, int out_size, void* d_ws, size_t ws_size,
                              hipStream_t stream)
{
    const float* hs        = (const float*)d_in[0];
    const float* in_proj_w = (const float*)d_in[1];
    const float* conv_w    = (const float*)d_in[2];
    const float* conv_b    = (const float*)d_in[3];
    const float* x_proj_w  = (const float*)d_in[4];
    const float* dt_proj_w = (const float*)d_in[5];
    const float* dt_proj_b = (const float*)d_in[6];
    const float* A_log     = (const float*)d_in[7];
    const float* D_param   = (const float*)d_in[8];
    const float* out_proj_w= (const float*)d_in[9];
    float* out = (float*)d_out;

    // ---- workspace layout (float offsets) ----
    float* xz    = (float*)d_ws;                              // 16,777,216 f
    unsigned short* u_bf = (unsigned short*)(xz + (size_t)16777216);  // 8.4M us
    float* xdbl  = (float*)((unsigned short*)u_bf + (size_t)M_ROWS * D_INNER); // 393216 f
    unsigned short* dt_bf = (unsigned short*)(xdbl + (size_t)M_ROWS * 96);     // 262144 us
    float* delta = (float*)(dt_bf + (size_t)M_ROWS * DT_RANK);                 // 8,388,608 f
    float* Pws   = delta + (size_t)M_ROWS * D_INNER;
    float* Qws   = Pws   + (size_t)N_BATCH * N_CHUNK * D_INNER * 16;
    float* Hin   = Qws   + (size_t)N_BATCH * N_CHUNK * D_INNER * 16;
    unsigned short* opw_bf = (unsigned short*)(Hin + (size_t)N_BATCH * N_CHUNK * D_INNER * 16);
    unsigned short* y_bf   = opw_bf + (size_t)D_MODEL * D_INNER;
    unsigned short* xpw_bf = y_bf   + (size_t)M_ROWS * D_INNER;
    unsigned short* dtw_bf = xpw_bf + (size_t)128 * D_INNER;
    // aliases (stream-ordered, non-overlapping lifetimes):
    unsigned short* hs_bf  = (unsigned short*)delta;           // dead after in_proj
    unsigned short* ipw_bf = hs_bf + (size_t)M_ROWS * D_MODEL; // dead after in_proj
    float* xp_part = (float*)y_bf;    // [8][4096][128] — dead after xproj_reduce
    float* op_part = xz;              // [2][4096][1024] — xz dead after scan1

    const dim3 blk(256);

    // 0) fp32 -> bf16 casts
    cvt_bf16_kernel<<<(M_ROWS * D_MODEL / 4 + 255) / 256, blk, 0, stream>>>(
        hs, hs_bf, M_ROWS * D_MODEL / 4);
    cvt_bf16_kernel<<<(2 * D_INNER * D_MODEL / 4 + 255) / 256, blk, 0, stream>>>(
        in_proj_w, ipw_bf, 2 * D_INNER * D_MODEL / 4);
    cvt_bf16_kernel<<<(D_MODEL * D_INNER / 4 + 255) / 256, blk, 0, stream>>>(
        out_proj_w, opw_bf, D_MODEL * D_INNER / 4);
    cvt_pad_xpw_kernel<<<(128 * D_INNER / 4 + 255) / 256, blk, 0, stream>>>(
        x_proj_w, xpw_bf);
    cvt_bf16_kernel<<<(D_INNER * DT_RANK / 4 + 255) / 256, blk, 0, stream>>>(
        dt_proj_w, dtw_bf, D_INNER * DT_RANK / 4);

    // 1) xz = hs @ in_proj_w^T   (bf16 MFMA)
    gemm_mfma_bt<0><<<dim3((2 * D_INNER) / 128, M_ROWS / 128, 1), blk, 0, stream>>>(
        hs_bf, ipw_bf, xz, nullptr, M_ROWS, 2 * D_INNER, D_MODEL, D_MODEL);

    // 2) u = silu(causal_conv(x) + conv_b)  (bf16 out)
    conv_silu_kernel<<<(M_ROWS * D_INNER) / 256, blk, 0, stream>>>(
        xz, conv_w, conv_b, u_bf);

    // 3) x_dbl = u @ x_proj_w^T   (bf16 MFMA, split-K=8, padded N=128)
    gemm_mfma_bt<0><<<dim3(1, M_ROWS / 128, XP_KSPLIT), blk, 0, stream>>>(
        u_bf, xpw_bf, xp_part, nullptr, M_ROWS, 128, D_INNER, XP_KLEN);
    xproj_reduce_kernel<<<(M_ROWS * 24 + 255) / 256, blk, 0, stream>>>(
        xp_part, xdbl, dt_bf);

    // 4) delta = softplus(dt @ dt_proj_w^T + dt_proj_b)   (bf16 MFMA, K=64)
    gemm_mfma_bt<1><<<dim3(D_INNER / 128, M_ROWS / 128, 1), blk, 0, stream>>>(
        dt_bf, dtw_bf, delta, dt_proj_b, M_ROWS, D_INNER, DT_RANK, DT_RANK);

    // 5) chunked selective scan (register-sequential, no LDS)
    const int scan_blocks = N_BATCH * (D_INNER / 256) * N_CHUNK;  // 512
    scan_seq_kernel<0><<<scan_blocks, blk, 0, stream>>>(
        delta, u_bf, xdbl, xz, A_log, D_param, Pws, Qws, nullptr, nullptr);
    scan_combine_kernel<<<(N_BATCH * D_INNER * 16) / 256, blk, 0, stream>>>(
        Pws, Qws, Hin);
    scan_seq_kernel<1><<<scan_blocks, blk, 0, stream>>>(
        delta, u_bf, xdbl, xz, A_log, D_param, nullptr, nullptr, Hin, y_bf);

    // 6) out = y @ out_proj_w^T   (bf16 MFMA, split-K=2)
    gemm_mfma_bt<0><<<dim3(D_MODEL / 128, M_ROWS / 128, OP_KSPLIT), blk, 0, stream>>>(
        y_bf, opw_bf, op_part, nullptr, M_ROWS, D_MODEL, D_INNER, OP_KLEN);
    oproj_reduce_kernel<<<(M_ROWS * D_MODEL / 4 + 255) / 256, blk, 0, stream>>>(
        op_part, out);
}